// Round 1
// baseline (1013.907 us; speedup 1.0000x reference)
//
#include <hip/hip_runtime.h>
#include <math.h>

// Problem constants (fixed by setup_inputs)
#define D_MODEL   256
#define D_FFN     1024
#define N_LEVELS  4
#define N_HEADS   8
#define N_POINTS  4
#define D_HEAD    32
#define BATCH     2
#define LQ        8192
#define S_TOTAL   21760            // 128*128 + 64*64 + 32*32 + 16*16
#define M_Q       (BATCH*LQ)       // 16384
#define M_V       (BATCH*S_TOTAL)  // 43520

// GEMM tile config
#define BM 32
#define BK 32

// ---------------------------------------------------------------------------
// Tiled f32 GEMM: out[M,N] = A[M,K] @ W[K,N] (+bias) with optional fused
// epilogues. Block computes BM rows x BN cols. 256 threads, thread (ty,tx)
// owns 4 rows x (2*NJ) cols laid out as col = j*64 + tx*2 + {0,1}.
// FUSEQ:   A := A + A2 elementwise (q = tgt + query_pos)
// RELU:    epilogue max(0, .)
// DO_LN:   epilogue v += resid; LayerNorm over the 256 cols (requires BN==256)
// DO_SOFTMAX: epilogue softmax over groups of 16 cols (requires BN==128)
// ---------------------------------------------------------------------------
template<int BN, bool FUSEQ, bool RELU, bool DO_LN, bool DO_SOFTMAX>
__global__ __launch_bounds__(256)
void gemm_kernel(const float* __restrict__ A, const float* __restrict__ A2,
                 const float* __restrict__ W, const float* __restrict__ bias,
                 const float* __restrict__ resid, const float* __restrict__ ln_g,
                 const float* __restrict__ ln_b, float* __restrict__ out,
                 int K, int ldW, int ldOut)
{
    constexpr int NJ   = BN / 64;        // float2 column groups per thread
    constexpr int WREP = (BK * BN) / 1024; // float4 W-loads per thread

    __shared__ float As[BK][BM];         // As[k][m] (transposed A tile)
    __shared__ float Ws[BK][BN];         // Ws[k][n]

    const int tid = threadIdx.x;
    const int tx  = tid & 31;
    const int ty  = tid >> 5;
    const int row0 = blockIdx.x * BM;
    const int nb0  = blockIdx.y * BN;

    float acc[4][2 * NJ];
#pragma unroll
    for (int i = 0; i < 4; i++)
#pragma unroll
        for (int j = 0; j < 2 * NJ; j++) acc[i][j] = 0.f;

    const int arow = tid >> 3;           // 0..31: which row this thread stages
    const int ak   = (tid & 7) * 4;      // k-offset of its float4
    const float* Aptr  = A  + (long)(row0 + arow) * K + ak;
    const float* A2ptr = A2 + (long)(row0 + arow) * K + ak;

    for (int kt = 0; kt < K; kt += BK) {
        // ---- stage tiles (global -> regs) ----
        float4 av = *(const float4*)(Aptr + kt);
        if (FUSEQ) {
            float4 bv = *(const float4*)(A2ptr + kt);
            av.x += bv.x; av.y += bv.y; av.z += bv.z; av.w += bv.w;
        }
        float4 wv[WREP];
#pragma unroll
        for (int r = 0; r < WREP; r++) {
            int li = r * 1024 + tid * 4;
            int wk = li / BN, wn = li % BN;
            wv[r] = *(const float4*)(W + (long)(kt + wk) * ldW + nb0 + wn);
        }
        __syncthreads();                 // previous tile fully consumed
        As[ak + 0][arow] = av.x; As[ak + 1][arow] = av.y;
        As[ak + 2][arow] = av.z; As[ak + 3][arow] = av.w;
#pragma unroll
        for (int r = 0; r < WREP; r++) {
            int li = r * 1024 + tid * 4;
            int wk = li / BN, wn = li % BN;
            *(float4*)&Ws[wk][wn] = wv[r];
        }
        __syncthreads();

        // ---- compute ----
#pragma unroll
        for (int kk = 0; kk < BK; kk++) {
            float4 a4 = *(const float4*)&As[kk][ty * 4];
            float am[4] = {a4.x, a4.y, a4.z, a4.w};
#pragma unroll
            for (int j = 0; j < NJ; j++) {
                float2 w2 = *(const float2*)&Ws[kk][j * 64 + tx * 2];
#pragma unroll
                for (int i = 0; i < 4; i++) {
                    acc[i][2 * j + 0] += am[i] * w2.x;
                    acc[i][2 * j + 1] += am[i] * w2.y;
                }
            }
        }
    }

    // ---- epilogues ----
    if (DO_SOFTMAX) {
        // BN == 128 == full N. Round-trip through LDS (reuse Ws as [32][128]).
        __syncthreads();
#pragma unroll
        for (int i = 0; i < 4; i++)
#pragma unroll
            for (int j = 0; j < NJ; j++)
#pragma unroll
                for (int u = 0; u < 2; u++) {
                    int c = j * 64 + tx * 2 + u;
                    Ws[ty * 4 + i][c] = acc[i][2 * j + u] + bias[c];
                }
        __syncthreads();
        const int row = tid >> 3;        // 0..31
        const int h   = tid & 7;         // 0..7
        float v[16], m = -1e30f;
#pragma unroll
        for (int k = 0; k < 16; k++) { v[k] = Ws[row][h * 16 + k]; m = fmaxf(m, v[k]); }
        float s = 0.f;
#pragma unroll
        for (int k = 0; k < 16; k++) { v[k] = __expf(v[k] - m); s += v[k]; }
        float inv = 1.f / s;
        float* op = out + (long)(row0 + row) * 128 + h * 16;
#pragma unroll
        for (int k = 0; k < 16; k++) op[k] = v[k] * inv;
        return;
    }

    if (DO_LN) {
        // BN == 256 == full N; ldOut == 256, nb0 == 0.
        float v[4][2 * NJ];
#pragma unroll
        for (int i = 0; i < 4; i++) {
            long row = row0 + ty * 4 + i;
            float s = 0.f, sq = 0.f;
#pragma unroll
            for (int j = 0; j < NJ; j++)
#pragma unroll
                for (int u = 0; u < 2; u++) {
                    int c = j * 64 + tx * 2 + u;
                    float x = acc[i][2 * j + u] + bias[c] + resid[row * 256 + c];
                    v[i][2 * j + u] = x;
                    s += x; sq += x * x;
                }
            // reduce over the 32 tx-lanes (same ty -> same 32-lane segment)
#pragma unroll
            for (int msk = 16; msk >= 1; msk >>= 1) {
                s  += __shfl_xor(s,  msk, 32);
                sq += __shfl_xor(sq, msk, 32);
            }
            float mean = s * (1.f / 256.f);
            float var  = sq * (1.f / 256.f) - mean * mean;
            float r    = rsqrtf(var + 1e-5f);
#pragma unroll
            for (int j = 0; j < NJ; j++) {
                int c = j * 64 + tx * 2;
                float2 o;
                o.x = (v[i][2 * j + 0] - mean) * r * ln_g[c + 0] + ln_b[c + 0];
                o.y = (v[i][2 * j + 1] - mean) * r * ln_g[c + 1] + ln_b[c + 1];
                *(float2*)&out[row * 256 + c] = o;
            }
        }
        return;
    }

    // plain / relu
#pragma unroll
    for (int i = 0; i < 4; i++) {
        long row = row0 + ty * 4 + i;
#pragma unroll
        for (int j = 0; j < NJ; j++) {
            int cl = j * 64 + tx * 2;
            float2 o;
            o.x = acc[i][2 * j + 0] + bias[nb0 + cl + 0];
            o.y = acc[i][2 * j + 1] + bias[nb0 + cl + 1];
            if (RELU) { o.x = fmaxf(o.x, 0.f); o.y = fmaxf(o.y, 0.f); }
            *(float2*)&out[row * ldOut + nb0 + cl] = o;
        }
    }
}

// ---------------------------------------------------------------------------
// Deformable bilinear sampling. One block per (b,q). Thread t = (h, d):
// h = t>>5 (head), d = t&31 (channel). 32 d-lanes gather contiguous 128B.
// ---------------------------------------------------------------------------
__global__ __launch_bounds__(256)
void sample_kernel(const float* __restrict__ refp, const float* __restrict__ offb,
                   const float* __restrict__ attn, const float* __restrict__ value,
                   float* __restrict__ tgt2)
{
    const int q = blockIdx.x;            // b*LQ + qi
    const int b = q >> 13;               // LQ = 8192
    const int t = threadIdx.x;
    const int h = t >> 5, d = t & 31;

    const int HW[N_LEVELS][2]  = {{128,128},{64,64},{32,32},{16,16}};
    const int LSTART[N_LEVELS] = {0, 16384, 20480, 21504};

    const float* offq  = offb + (long)q * 256 + h * 32;
    const float* attq  = attn + (long)q * 128 + h * 16;
    const float* vbase = value + (long)b * S_TOTAL * 256 + h * 32 + d;

    float acc = 0.f;
#pragma unroll
    for (int l = 0; l < N_LEVELS; l++) {
        const int Hl = HW[l][0], Wl = HW[l][1];
        const float rx = refp[((long)q * N_LEVELS + l) * 2 + 0];
        const float ry = refp[((long)q * N_LEVELS + l) * 2 + 1];
        const float fx = rx * Wl - 0.5f;
        const float fy = ry * Hl - 0.5f;
        const float* vl = vbase + (long)LSTART[l] * 256;
#pragma unroll
        for (int p = 0; p < N_POINTS; p++) {
            float x = fx + offq[l * 8 + p * 2 + 0];
            float y = fy + offq[l * 8 + p * 2 + 1];
            float a = attq[l * 4 + p];
            float x0 = floorf(x), y0 = floorf(y);
            float wx = x - x0, wy = y - y0;
            int ix = (int)x0, iy = (int)y0;
            float w00 = (1.f - wx) * (1.f - wy) * a;
            float w10 = wx * (1.f - wy) * a;
            float w01 = (1.f - wx) * wy * a;
            float w11 = wx * wy * a;
            bool vx0 = (ix >= 0)     && (ix < Wl);
            bool vx1 = (ix + 1 >= 0) && (ix + 1 < Wl);
            if (iy >= 0 && iy < Hl) {
                const float* rowp = vl + (long)(iy * Wl) * 256;
                if (vx0) acc += w00 * rowp[(long)ix * 256];
                if (vx1) acc += w10 * rowp[(long)(ix + 1) * 256];
            }
            if (iy + 1 >= 0 && iy + 1 < Hl) {
                const float* rowp = vl + (long)((iy + 1) * Wl) * 256;
                if (vx0) acc += w01 * rowp[(long)ix * 256];
                if (vx1) acc += w11 * rowp[(long)(ix + 1) * 256];
            }
        }
    }
    tgt2[(long)q * 256 + h * 32 + d] = acc;
}

// ---------------------------------------------------------------------------
extern "C" void kernel_launch(void* const* d_in, const int* in_sizes, int n_in,
                              void* d_out, int out_size, void* d_ws, size_t ws_size,
                              hipStream_t stream) {
    const float* tgt   = (const float*)d_in[0];
    const float* qpos  = (const float*)d_in[1];
    const float* refp  = (const float*)d_in[2];
    const float* src   = (const float*)d_in[3];
    // d_in[4] spatial_shapes, d_in[5] level_start_index: fixed, hardcoded.
    const float* W_value = (const float*)d_in[6];
    const float* b_value = (const float*)d_in[7];
    const float* W_off   = (const float*)d_in[8];
    const float* b_off   = (const float*)d_in[9];
    const float* W_attn  = (const float*)d_in[10];
    const float* b_attn  = (const float*)d_in[11];
    const float* W_out   = (const float*)d_in[12];
    const float* b_out   = (const float*)d_in[13];
    const float* ln1_g   = (const float*)d_in[14];
    const float* ln1_b   = (const float*)d_in[15];
    const float* W1      = (const float*)d_in[16];
    const float* b1      = (const float*)d_in[17];
    const float* W2      = (const float*)d_in[18];
    const float* b2      = (const float*)d_in[19];
    const float* ln3_g   = (const float*)d_in[20];
    const float* ln3_b   = (const float*)d_in[21];
    float* out = (float*)d_out;

    // workspace layout (floats)
    float* value = (float*)d_ws;                    // 43520*256
    float* offb  = value + (long)M_V * 256;         // 16384*256
    float* attn  = offb  + (long)M_Q * 256;         // 16384*128
    float* tgt2  = attn  + (long)M_Q * 128;         // 16384*256
    float* x     = tgt2  + (long)M_Q * 256;         // 16384*256
    float* hbuf  = x     + (long)M_Q * 256;         // 16384*1024

    dim3 blk(256);

    // 1) value = src @ W_value + b_value
    gemm_kernel<256, false, false, false, false><<<dim3(M_V / BM, 1), blk, 0, stream>>>(
        src, nullptr, W_value, b_value, nullptr, nullptr, nullptr, value, 256, 256, 256);

    // 2) off = (tgt+qpos) @ W_off + b_off
    gemm_kernel<256, true, false, false, false><<<dim3(M_Q / BM, 1), blk, 0, stream>>>(
        tgt, qpos, W_off, b_off, nullptr, nullptr, nullptr, offb, 256, 256, 256);

    // 3) attn = softmax((tgt+qpos) @ W_attn + b_attn)
    gemm_kernel<128, true, false, false, true><<<dim3(M_Q / BM, 1), blk, 0, stream>>>(
        tgt, qpos, W_attn, b_attn, nullptr, nullptr, nullptr, attn, 256, 128, 128);

    // 4) deformable sampling -> tgt2 (pre out-proj)
    sample_kernel<<<dim3(M_Q), blk, 0, stream>>>(refp, offb, attn, value, tgt2);

    // 5) x = LN1(tgt + tgt2 @ W_out + b_out)
    gemm_kernel<256, false, false, true, false><<<dim3(M_Q / BM, 1), blk, 0, stream>>>(
        tgt2, nullptr, W_out, b_out, tgt, ln1_g, ln1_b, x, 256, 256, 256);

    // 6) h = relu(x @ W1 + b1)
    gemm_kernel<256, false, true, false, false><<<dim3(M_Q / BM, D_FFN / 256), blk, 0, stream>>>(
        x, nullptr, W1, b1, nullptr, nullptr, nullptr, hbuf, 256, D_FFN, D_FFN);

    // 7) out = LN3(x + h @ W2 + b2)
    gemm_kernel<256, false, false, true, false><<<dim3(M_Q / BM, 1), blk, 0, stream>>>(
        hbuf, nullptr, W2, b2, x, ln3_g, ln3_b, out, D_FFN, 256, 256);
}

// Round 2
// 498.491 us; speedup vs baseline: 2.0340x; 2.0340x over previous
//
#include <hip/hip_runtime.h>
#include <hip/hip_bf16.h>
#include <math.h>

// Problem constants (fixed by setup_inputs)
#define D_MODEL   256
#define D_FFN     1024
#define N_LEVELS  4
#define N_HEADS   8
#define N_POINTS  4
#define BATCH     2
#define LQ        8192
#define S_TOTAL   21760            // 128*128 + 64*64 + 32*32 + 16*16
#define M_Q       (BATCH*LQ)       // 16384
#define M_V       (BATCH*S_TOTAL)  // 43520

typedef __attribute__((ext_vector_type(8))) short bf16x8;   // 8 bf16 = 4 VGPRs
typedef __attribute__((ext_vector_type(4))) float floatx4;  // mfma C/D

__device__ __forceinline__ void gld_lds16(const void* g, void* l) {
    __builtin_amdgcn_global_load_lds(
        (const __attribute__((address_space(1))) void*)g,
        (__attribute__((address_space(3))) void*)l, 16, 0, 0);
}

// ---------------------------------------------------------------------------
// bf16 MFMA GEMM: out[M,N] = A[M,K] @ B[K,N] (+bias), B given TRANSPOSED as
// Bt[N][K] bf16. Block tile 128 x BN, 4 waves stacked on M (wave tile 32xBN),
// BK=32 with v_mfma_f32_16x16x32_bf16. global_load_lds(16B) staging.
// Fragment layouts (verified, learn_hip m89/m91):
//   A: lane holds A[m=lane&15][k=quad*8+j], 16B contiguous in LDS row
//   B: lane holds B[k=quad*8+j][n=lane&15] -> Bt LDS row [n][k], 16B contig
//   C/D: col=lane&15, row=quad*4+reg
// EPI: 0=f32 out, 1=bf16 out, 2=relu->bf16, 3=group-softmax(16)->f32 (BN=128),
//      4=residual+LayerNorm(256)->f32 (+optional bf16 copy)
// ---------------------------------------------------------------------------
template<int BN, int EPI>
__global__ __launch_bounds__(256)
void mfma_gemm(const __hip_bfloat16* __restrict__ A,
               const __hip_bfloat16* __restrict__ Bt,
               const float* __restrict__ bias,
               const float* __restrict__ resid,
               const float* __restrict__ lng, const float* __restrict__ lnb,
               float* __restrict__ outf, __hip_bfloat16* __restrict__ outb,
               int K, int ldOut)
{
    constexpr int NT  = BN / 16;   // 16x16 col tiles per wave row
    constexpr int BCH = BN / 64;   // 1KB B-staging chunks per wave

    const int tid  = threadIdx.x;
    const int w    = tid >> 6;
    const int lane = tid & 63;
    const int quad = lane >> 4;
    const int l15  = lane & 15;
    const int row0 = blockIdx.x * 128;
    const int nb0  = blockIdx.y * BN;

    __shared__ alignas(16) short As[128 * 32];   // [row][k], 64B rows
    __shared__ alignas(16) short Bs[BN * 32];    // [n][k],   64B rows

    floatx4 acc[2][NT];
#pragma unroll
    for (int mi = 0; mi < 2; mi++)
#pragma unroll
        for (int ni = 0; ni < NT; ni++) acc[mi][ni] = (floatx4){0.f, 0.f, 0.f, 0.f};

    const size_t K2 = (size_t)K * 2;  // row stride in bytes

    // staging addresses: chunk c covers LDS bytes [c*1024, c*1024+1024)
    const char* gA[2]; short* lA[2];
#pragma unroll
    for (int i = 0; i < 2; i++) {
        int o = (w * 2 + i) * 1024 + lane * 16;
        gA[i] = (const char*)A + (size_t)(row0 + (o >> 6)) * K2 + (o & 63);
        lA[i] = &As[(w * 2 + i) * 512];
    }
    const char* gB[BCH]; short* lB[BCH];
#pragma unroll
    for (int j = 0; j < BCH; j++) {
        int o = (w * BCH + j) * 1024 + lane * 16;
        gB[j] = (const char*)Bt + (size_t)(nb0 + (o >> 6)) * K2 + (o & 63);
        lB[j] = &Bs[(w * BCH + j) * 512];
    }

    for (int kt = 0; kt < K; kt += 32) {
        const size_t kb = (size_t)kt * 2;
#pragma unroll
        for (int i = 0; i < 2; i++)   gld_lds16(gA[i] + kb, lA[i]);
#pragma unroll
        for (int j = 0; j < BCH; j++) gld_lds16(gB[j] + kb, lB[j]);
        __syncthreads();   // drains vmcnt (async LDS stores) + barrier

        bf16x8 af[2];
        af[0] = *(const bf16x8*)&As[(w * 32      + l15) * 32 + quad * 8];
        af[1] = *(const bf16x8*)&As[(w * 32 + 16 + l15) * 32 + quad * 8];
#pragma unroll
        for (int ni = 0; ni < NT; ni++) {
            bf16x8 bfr = *(const bf16x8*)&Bs[(ni * 16 + l15) * 32 + quad * 8];
            acc[0][ni] = __builtin_amdgcn_mfma_f32_16x16x32_bf16(af[0], bfr, acc[0][ni], 0, 0, 0);
            acc[1][ni] = __builtin_amdgcn_mfma_f32_16x16x32_bf16(af[1], bfr, acc[1][ni], 0, 0, 0);
        }
        __syncthreads();   // all frags consumed before restaging
    }

    // ---- epilogue ----
    float bias_c[NT];
#pragma unroll
    for (int ni = 0; ni < NT; ni++) bias_c[ni] = bias[nb0 + ni * 16 + l15];

    if (EPI == 4) {  // residual + LayerNorm over 256 cols (BN==256, nb0==0)
        float gv[NT], bv[NT];
#pragma unroll
        for (int ni = 0; ni < NT; ni++) { gv[ni] = lng[ni * 16 + l15]; bv[ni] = lnb[ni * 16 + l15]; }
#pragma unroll
        for (int mi = 0; mi < 2; mi++)
#pragma unroll
            for (int r = 0; r < 4; r++) {
                int row = row0 + w * 32 + mi * 16 + quad * 4 + r;
                size_t rb = (size_t)row * 256;
                float s = 0.f, sq = 0.f, vv[NT];
#pragma unroll
                for (int ni = 0; ni < NT; ni++) {
                    float v = acc[mi][ni][r] + bias_c[ni] + resid[rb + ni * 16 + l15];
                    vv[ni] = v; s += v; sq += v * v;
                }
#pragma unroll
                for (int msk = 1; msk <= 8; msk <<= 1) {
                    s += __shfl_xor(s, msk); sq += __shfl_xor(sq, msk);
                }
                float mean = s * (1.f / 256.f);
                float var  = sq * (1.f / 256.f) - mean * mean;
                float rstd = rsqrtf(var + 1e-5f);
#pragma unroll
                for (int ni = 0; ni < NT; ni++) {
                    float o = (vv[ni] - mean) * rstd * gv[ni] + bv[ni];
                    outf[rb + ni * 16 + l15] = o;
                    if (outb) outb[rb + ni * 16 + l15] = __float2bfloat16(o);
                }
            }
        return;
    }

    if (EPI == 3) {  // softmax over groups of 16 cols == one ni-tile (BN==128)
#pragma unroll
        for (int mi = 0; mi < 2; mi++)
#pragma unroll
            for (int r = 0; r < 4; r++) {
                int row = row0 + w * 32 + mi * 16 + quad * 4 + r;
                size_t rb = (size_t)row * 128;
#pragma unroll
                for (int ni = 0; ni < NT; ni++) {
                    float v = acc[mi][ni][r] + bias_c[ni];
                    float m = v;
#pragma unroll
                    for (int msk = 1; msk <= 8; msk <<= 1) m = fmaxf(m, __shfl_xor(m, msk));
                    float e = __expf(v - m);
                    float ssum = e;
#pragma unroll
                    for (int msk = 1; msk <= 8; msk <<= 1) ssum += __shfl_xor(ssum, msk);
                    outf[rb + ni * 16 + l15] = e / ssum;
                }
            }
        return;
    }

    // EPI 0/1/2: plain / bf16 / relu-bf16
#pragma unroll
    for (int mi = 0; mi < 2; mi++)
#pragma unroll
        for (int r = 0; r < 4; r++) {
            int row = row0 + w * 32 + mi * 16 + quad * 4 + r;
            size_t rb = (size_t)row * ldOut + nb0;
#pragma unroll
            for (int ni = 0; ni < NT; ni++) {
                float v = acc[mi][ni][r] + bias_c[ni];
                if (EPI == 2) v = fmaxf(v, 0.f);
                if (EPI == 0) outf[rb + ni * 16 + l15] = v;
                else          outb[rb + ni * 16 + l15] = __float2bfloat16(v);
            }
        }
}

// ---------------------------------------------------------------------------
// Weight transpose + f32->bf16: out[n][k] = in[k][n]. One 32x32 tile/block,
// six weights batched into one launch via linear tile id.
// ---------------------------------------------------------------------------
__global__ __launch_bounds__(256)
void transpose_cvt(const float* w0, const float* w1, const float* w2,
                   const float* w3, const float* w4, const float* w5,
                   __hip_bfloat16* o0, __hip_bfloat16* o1, __hip_bfloat16* o2,
                   __hip_bfloat16* o3, __hip_bfloat16* o4, __hip_bfloat16* o5)
{
    int t = blockIdx.x;
    const float* src; __hip_bfloat16* dst; int Kd, Nd, tl;
    if      (t < 64)  { src = w0; dst = o0; Kd = 256;  Nd = 256;  tl = t; }
    else if (t < 128) { src = w1; dst = o1; Kd = 256;  Nd = 256;  tl = t - 64; }
    else if (t < 160) { src = w2; dst = o2; Kd = 256;  Nd = 128;  tl = t - 128; }
    else if (t < 224) { src = w3; dst = o3; Kd = 256;  Nd = 256;  tl = t - 160; }
    else if (t < 480) { src = w4; dst = o4; Kd = 256;  Nd = 1024; tl = t - 224; }
    else              { src = w5; dst = o5; Kd = 1024; Nd = 256;  tl = t - 480; }
    int ntn = Nd >> 5;
    int kt = tl / ntn, nt = tl - kt * ntn;
    __shared__ float T[32][33];
    int tx = threadIdx.x & 31, ty = threadIdx.x >> 5;
#pragma unroll
    for (int i = 0; i < 4; i++) {
        int k = kt * 32 + ty + i * 8;
        T[tx][ty + i * 8] = src[(size_t)k * Nd + nt * 32 + tx];   // T[n_l][k_l]
    }
    __syncthreads();
#pragma unroll
    for (int i = 0; i < 4; i++) {
        int n = nt * 32 + ty + i * 8;
        dst[(size_t)n * Kd + kt * 32 + tx] = __float2bfloat16(T[ty + i * 8][tx]);
    }
}

// elementwise f32 -> bf16 (4/thread)
struct alignas(8) bh4 { __hip_bfloat16 a, b, c, d; };
__global__ __launch_bounds__(256)
void cvt4(const float* __restrict__ in, __hip_bfloat16* __restrict__ o, int n4)
{
    int i = blockIdx.x * 256 + threadIdx.x;
    if (i >= n4) return;
    float4 v = ((const float4*)in)[i];
    ((bh4*)o)[i] = { __float2bfloat16(v.x), __float2bfloat16(v.y),
                     __float2bfloat16(v.z), __float2bfloat16(v.w) };
}

// q = tgt + query_pos -> bf16 (4/thread)
__global__ __launch_bounds__(256)
void addcvt4(const float* __restrict__ a, const float* __restrict__ b,
             __hip_bfloat16* __restrict__ o, int n4)
{
    int i = blockIdx.x * 256 + threadIdx.x;
    if (i >= n4) return;
    float4 x = ((const float4*)a)[i];
    float4 y = ((const float4*)b)[i];
    ((bh4*)o)[i] = { __float2bfloat16(x.x + y.x), __float2bfloat16(x.y + y.y),
                     __float2bfloat16(x.z + y.z), __float2bfloat16(x.w + y.w) };
}

// ---------------------------------------------------------------------------
// Deformable bilinear sampling (bf16 value). One block per (b,q).
// Thread t = (h, d): 32 d-lanes gather contiguous 64B bf16 segments.
// ---------------------------------------------------------------------------
__global__ __launch_bounds__(256)
void sample_kernel(const float* __restrict__ refp, const float* __restrict__ offb,
                   const float* __restrict__ attn, const __hip_bfloat16* __restrict__ value,
                   __hip_bfloat16* __restrict__ tgt2)
{
    const int q = blockIdx.x;            // b*LQ + qi
    const int b = q >> 13;               // LQ = 8192
    const int t = threadIdx.x;
    const int h = t >> 5, d = t & 31;

    const int HW[N_LEVELS][2]  = {{128,128},{64,64},{32,32},{16,16}};
    const int LSTART[N_LEVELS] = {0, 16384, 20480, 21504};

    const float* offq = offb + (size_t)q * 256 + h * 32;
    const float* attq = attn + (size_t)q * 128 + h * 16;
    const __hip_bfloat16* vbase = value + (size_t)b * S_TOTAL * 256 + h * 32 + d;

    float acc = 0.f;
#pragma unroll
    for (int l = 0; l < N_LEVELS; l++) {
        const int Hl = HW[l][0], Wl = HW[l][1];
        const float rx = refp[((size_t)q * N_LEVELS + l) * 2 + 0];
        const float ry = refp[((size_t)q * N_LEVELS + l) * 2 + 1];
        const float fx = rx * Wl - 0.5f;
        const float fy = ry * Hl - 0.5f;
        const __hip_bfloat16* vl = vbase + (size_t)LSTART[l] * 256;
#pragma unroll
        for (int p = 0; p < N_POINTS; p++) {
            float x = fx + offq[l * 8 + p * 2 + 0];
            float y = fy + offq[l * 8 + p * 2 + 1];
            float a = attq[l * 4 + p];
            float x0 = floorf(x), y0 = floorf(y);
            float wx = x - x0, wy = y - y0;
            int ix = (int)x0, iy = (int)y0;
            float w00 = (1.f - wx) * (1.f - wy) * a;
            float w10 = wx * (1.f - wy) * a;
            float w01 = (1.f - wx) * wy * a;
            float w11 = wx * wy * a;
            bool vx0 = (ix >= 0)     && (ix < Wl);
            bool vx1 = (ix + 1 >= 0) && (ix + 1 < Wl);
            if (iy >= 0 && iy < Hl) {
                const __hip_bfloat16* rowp = vl + (size_t)(iy * Wl) * 256;
                if (vx0) acc += w00 * __bfloat162float(rowp[(size_t)ix * 256]);
                if (vx1) acc += w10 * __bfloat162float(rowp[(size_t)(ix + 1) * 256]);
            }
            if (iy + 1 >= 0 && iy + 1 < Hl) {
                const __hip_bfloat16* rowp = vl + (size_t)((iy + 1) * Wl) * 256;
                if (vx0) acc += w01 * __bfloat162float(rowp[(size_t)ix * 256]);
                if (vx1) acc += w11 * __bfloat162float(rowp[(size_t)(ix + 1) * 256]);
            }
        }
    }
    tgt2[(size_t)q * 256 + h * 32 + d] = __float2bfloat16(acc);
}

// ---------------------------------------------------------------------------
extern "C" void kernel_launch(void* const* d_in, const int* in_sizes, int n_in,
                              void* d_out, int out_size, void* d_ws, size_t ws_size,
                              hipStream_t stream) {
    const float* tgt     = (const float*)d_in[0];
    const float* qpos    = (const float*)d_in[1];
    const float* refp    = (const float*)d_in[2];
    const float* src     = (const float*)d_in[3];
    const float* W_value = (const float*)d_in[6];
    const float* b_value = (const float*)d_in[7];
    const float* W_off   = (const float*)d_in[8];
    const float* b_off   = (const float*)d_in[9];
    const float* W_attn  = (const float*)d_in[10];
    const float* b_attn  = (const float*)d_in[11];
    const float* W_out   = (const float*)d_in[12];
    const float* b_out   = (const float*)d_in[13];
    const float* ln1_g   = (const float*)d_in[14];
    const float* ln1_b   = (const float*)d_in[15];
    const float* W1      = (const float*)d_in[16];
    const float* b1      = (const float*)d_in[17];
    const float* W2      = (const float*)d_in[18];
    const float* b2      = (const float*)d_in[19];
    const float* ln3_g   = (const float*)d_in[20];
    const float* ln3_b   = (const float*)d_in[21];
    float* out = (float*)d_out;

    // workspace layout
    char* p = (char*)d_ws;
    auto nxt = [&](size_t b) { char* r = p; p += (b + 255) & ~(size_t)255; return r; };
    __hip_bfloat16* Wvt    = (__hip_bfloat16*)nxt((size_t)256 * 256 * 2);
    __hip_bfloat16* Wofft  = (__hip_bfloat16*)nxt((size_t)256 * 256 * 2);
    __hip_bfloat16* Wattnt = (__hip_bfloat16*)nxt((size_t)128 * 256 * 2);
    __hip_bfloat16* Woutt  = (__hip_bfloat16*)nxt((size_t)256 * 256 * 2);
    __hip_bfloat16* W1t    = (__hip_bfloat16*)nxt((size_t)1024 * 256 * 2);
    __hip_bfloat16* W2t    = (__hip_bfloat16*)nxt((size_t)256 * 1024 * 2);
    __hip_bfloat16* srcb   = (__hip_bfloat16*)nxt((size_t)M_V * 256 * 2);
    __hip_bfloat16* qb     = (__hip_bfloat16*)nxt((size_t)M_Q * 256 * 2);
    __hip_bfloat16* valueb = (__hip_bfloat16*)nxt((size_t)M_V * 256 * 2);
    float*          offb   = (float*)nxt((size_t)M_Q * 256 * 4);
    float*          attn   = (float*)nxt((size_t)M_Q * 128 * 4);
    __hip_bfloat16* tgt2b  = (__hip_bfloat16*)nxt((size_t)M_Q * 256 * 2);
    float*          x      = (float*)nxt((size_t)M_Q * 256 * 4);
    __hip_bfloat16* xb     = (__hip_bfloat16*)nxt((size_t)M_Q * 256 * 2);
    __hip_bfloat16* hb     = (__hip_bfloat16*)nxt((size_t)M_Q * 1024 * 2);

    dim3 blk(256);

    // 0) weight transpose+cvt, activation converts
    transpose_cvt<<<dim3(736), blk, 0, stream>>>(W_value, W_off, W_attn, W_out, W1, W2,
                                                 Wvt, Wofft, Wattnt, Woutt, W1t, W2t);
    cvt4<<<dim3((M_V * 256 / 4 + 255) / 256), blk, 0, stream>>>(src, srcb, M_V * 256 / 4);
    addcvt4<<<dim3((M_Q * 256 / 4 + 255) / 256), blk, 0, stream>>>(tgt, qpos, qb, M_Q * 256 / 4);

    // 1) value = src @ W_value + b_value  -> bf16
    mfma_gemm<256, 1><<<dim3(M_V / 128, 1), blk, 0, stream>>>(
        srcb, Wvt, b_value, nullptr, nullptr, nullptr, nullptr, valueb, 256, 256);

    // 2) off = q @ W_off + b_off -> f32
    mfma_gemm<256, 0><<<dim3(M_Q / 128, 1), blk, 0, stream>>>(
        qb, Wofft, b_off, nullptr, nullptr, nullptr, offb, nullptr, 256, 256);

    // 3) attn = softmax16(q @ W_attn + b_attn) -> f32
    mfma_gemm<128, 3><<<dim3(M_Q / 128, 1), blk, 0, stream>>>(
        qb, Wattnt, b_attn, nullptr, nullptr, nullptr, attn, nullptr, 256, 128);

    // 4) deformable sampling -> tgt2 (bf16)
    sample_kernel<<<dim3(M_Q), blk, 0, stream>>>(refp, offb, attn, valueb, tgt2b);

    // 5) x = LN1(tgt + tgt2 @ W_out + b_out) -> f32 + bf16
    mfma_gemm<256, 4><<<dim3(M_Q / 128, 1), blk, 0, stream>>>(
        tgt2b, Woutt, b_out, tgt, ln1_g, ln1_b, x, xb, 256, 256);

    // 6) h = relu(x @ W1 + b1) -> bf16
    mfma_gemm<256, 2><<<dim3(M_Q / 128, 4), blk, 0, stream>>>(
        xb, W1t, b1, nullptr, nullptr, nullptr, nullptr, hb, 256, 1024);

    // 7) out = LN3(x + h @ W2 + b2) -> f32
    mfma_gemm<256, 4><<<dim3(M_Q / 128, 1), blk, 0, stream>>>(
        hb, W2t, b2, x, ln3_g, ln3_b, out, nullptr, 1024, 256);
}

// Round 3
// 314.384 us; speedup vs baseline: 3.2251x; 1.5856x over previous
//
#include <hip/hip_runtime.h>
#include <hip/hip_bf16.h>
#include <math.h>

// Problem constants (fixed by setup_inputs)
#define D_MODEL   256
#define D_FFN     1024
#define N_LEVELS  4
#define N_HEADS   8
#define N_POINTS  4
#define BATCH     2
#define LQ        8192
#define S_TOTAL   21760            // 128*128 + 64*64 + 32*32 + 16*16
#define M_Q       (BATCH*LQ)       // 16384
#define M_V       (BATCH*S_TOTAL)  // 43520

typedef __attribute__((ext_vector_type(8))) short bf16x8;   // 8 bf16 = 4 VGPRs
typedef __attribute__((ext_vector_type(4))) float floatx4;  // mfma C/D

__device__ __forceinline__ void gld_lds16(const void* g, void* l) {
    __builtin_amdgcn_global_load_lds(
        (const __attribute__((address_space(1))) void*)g,
        (__attribute__((address_space(3))) void*)l, 16, 0, 0);
}

// ---------------------------------------------------------------------------
// bf16 MFMA GEMM: out[M,N] = A[M,K] @ B[K,N] (+bias), B TRANSPOSED as Bt[N][K]
// bf16. Block tile BM x BN, 4 waves stacked on M (wave tile (BM/4) x BN),
// BK=32 with v_mfma_f32_16x16x32_bf16, global_load_lds(16B) staging.
// Fragment layouts (verified, learn_hip m89/m91):
//   A: lane holds A[m=lane&15][k=quad*8+j] -> 16B contiguous LDS row
//   B: lane holds B[k=quad*8+j][n=lane&15] -> Bt LDS row [n][k], 16B contig
//   C/D: col=lane&15, row=quad*4+reg
// EPI: 0=f32 out, 1=bf16 out, 2=relu->bf16,
//      4=residual+LayerNorm(256)->f32 (+opt bf16 copy)  [BN==256]
//      5=merged off/attn: blockIdx.y<2 -> plain f32 (ld 256); y==2 ->
//        group-softmax(16)->outf2 (ld 128)               [BN==128]
// ---------------------------------------------------------------------------
template<int BM, int BN, int EPI>
__global__ __launch_bounds__(256)
void mfma_gemm(const __hip_bfloat16* __restrict__ A,
               const __hip_bfloat16* __restrict__ Bt,
               const float* __restrict__ bias, const float* __restrict__ bias2,
               const float* __restrict__ resid,
               const float* __restrict__ lng, const float* __restrict__ lnb,
               float* __restrict__ outf, __hip_bfloat16* __restrict__ outb,
               float* __restrict__ outf2,
               int K, int ldOut)
{
    constexpr int NT  = BN / 16;   // 16x16 col tiles per wave
    constexpr int AF  = BM / 64;   // A frags per wave (wave rows = AF*16)
    constexpr int BCH = BN / 64;   // 1KB B-staging chunks per wave

    const int tid  = threadIdx.x;
    const int w    = tid >> 6;
    const int lane = tid & 63;
    const int quad = lane >> 4;
    const int l15  = lane & 15;
    const int row0 = blockIdx.x * BM;
    const int nb0  = blockIdx.y * BN;

    __shared__ alignas(16) short As[BM * 32];   // [row][k], 64B rows
    __shared__ alignas(16) short Bs[BN * 32];   // [n][k],   64B rows

    floatx4 acc[AF][NT];
#pragma unroll
    for (int mi = 0; mi < AF; mi++)
#pragma unroll
        for (int ni = 0; ni < NT; ni++) acc[mi][ni] = (floatx4){0.f, 0.f, 0.f, 0.f};

    const size_t K2 = (size_t)K * 2;  // row stride in bytes

    const char* gA[AF]; short* lA[AF];
#pragma unroll
    for (int i = 0; i < AF; i++) {
        int o = (w * AF + i) * 1024 + lane * 16;
        gA[i] = (const char*)A + (size_t)(row0 + (o >> 6)) * K2 + (o & 63);
        lA[i] = &As[(w * AF + i) * 512];
    }
    const char* gB[BCH]; short* lB[BCH];
#pragma unroll
    for (int j = 0; j < BCH; j++) {
        int o = (w * BCH + j) * 1024 + lane * 16;
        gB[j] = (const char*)Bt + (size_t)(nb0 + (o >> 6)) * K2 + (o & 63);
        lB[j] = &Bs[(w * BCH + j) * 512];
    }

    for (int kt = 0; kt < K; kt += 32) {
        const size_t kb = (size_t)kt * 2;
#pragma unroll
        for (int i = 0; i < AF; i++)  gld_lds16(gA[i] + kb, lA[i]);
#pragma unroll
        for (int j = 0; j < BCH; j++) gld_lds16(gB[j] + kb, lB[j]);
        __syncthreads();   // drains vmcnt (async LDS stores) + barrier

        bf16x8 af[AF];
#pragma unroll
        for (int mi = 0; mi < AF; mi++)
            af[mi] = *(const bf16x8*)&As[(w * (AF * 16) + mi * 16 + l15) * 32 + quad * 8];
#pragma unroll
        for (int ni = 0; ni < NT; ni++) {
            bf16x8 bfr = *(const bf16x8*)&Bs[(ni * 16 + l15) * 32 + quad * 8];
#pragma unroll
            for (int mi = 0; mi < AF; mi++)
                acc[mi][ni] = __builtin_amdgcn_mfma_f32_16x16x32_bf16(af[mi], bfr, acc[mi][ni], 0, 0, 0);
        }
        __syncthreads();   // all frags consumed before restaging
    }

    // ---- epilogue ----
    const bool soft = (EPI == 5) && (blockIdx.y == 2);
    const float* bp = soft ? bias2 : bias;
    const int bcol0 = soft ? 0 : nb0;
    float bias_c[NT];
#pragma unroll
    for (int ni = 0; ni < NT; ni++) bias_c[ni] = bp[bcol0 + ni * 16 + l15];

    if (EPI == 4) {  // residual + LayerNorm over 256 cols (BN==256, nb0==0)
        float gv[NT], bv[NT];
#pragma unroll
        for (int ni = 0; ni < NT; ni++) { gv[ni] = lng[ni * 16 + l15]; bv[ni] = lnb[ni * 16 + l15]; }
#pragma unroll
        for (int mi = 0; mi < AF; mi++)
#pragma unroll
            for (int r = 0; r < 4; r++) {
                int row = row0 + w * (AF * 16) + mi * 16 + quad * 4 + r;
                size_t rb = (size_t)row * 256;
                float s = 0.f, sq = 0.f, vv[NT];
#pragma unroll
                for (int ni = 0; ni < NT; ni++) {
                    float v = acc[mi][ni][r] + bias_c[ni] + resid[rb + ni * 16 + l15];
                    vv[ni] = v; s += v; sq += v * v;
                }
#pragma unroll
                for (int msk = 1; msk <= 8; msk <<= 1) {
                    s += __shfl_xor(s, msk); sq += __shfl_xor(sq, msk);
                }
                float mean = s * (1.f / 256.f);
                float var  = sq * (1.f / 256.f) - mean * mean;
                float rstd = rsqrtf(var + 1e-5f);
#pragma unroll
                for (int ni = 0; ni < NT; ni++) {
                    float o = (vv[ni] - mean) * rstd * gv[ni] + bv[ni];
                    outf[rb + ni * 16 + l15] = o;
                    if (outb) outb[rb + ni * 16 + l15] = __float2bfloat16(o);
                }
            }
        return;
    }

    if (EPI == 5) {
        if (soft) {  // group-softmax(16) -> outf2 (ld 128)
#pragma unroll
            for (int mi = 0; mi < AF; mi++)
#pragma unroll
                for (int r = 0; r < 4; r++) {
                    int row = row0 + w * (AF * 16) + mi * 16 + quad * 4 + r;
                    size_t rb = (size_t)row * 128;
#pragma unroll
                    for (int ni = 0; ni < NT; ni++) {
                        float v = acc[mi][ni][r] + bias_c[ni];
                        float m = v;
#pragma unroll
                        for (int msk = 1; msk <= 8; msk <<= 1) m = fmaxf(m, __shfl_xor(m, msk));
                        float e = __expf(v - m);
                        float ssum = e;
#pragma unroll
                        for (int msk = 1; msk <= 8; msk <<= 1) ssum += __shfl_xor(ssum, msk);
                        outf2[rb + ni * 16 + l15] = e / ssum;
                    }
                }
        } else {     // plain f32 -> outf (ld 256)
#pragma unroll
            for (int mi = 0; mi < AF; mi++)
#pragma unroll
                for (int r = 0; r < 4; r++) {
                    int row = row0 + w * (AF * 16) + mi * 16 + quad * 4 + r;
                    size_t rb = (size_t)row * 256 + nb0;
#pragma unroll
                    for (int ni = 0; ni < NT; ni++)
                        outf[rb + ni * 16 + l15] = acc[mi][ni][r] + bias_c[ni];
                }
        }
        return;
    }

    // EPI 0/1/2: plain / bf16 / relu-bf16
#pragma unroll
    for (int mi = 0; mi < AF; mi++)
#pragma unroll
        for (int r = 0; r < 4; r++) {
            int row = row0 + w * (AF * 16) + mi * 16 + quad * 4 + r;
            size_t rb = (size_t)row * ldOut + nb0;
#pragma unroll
            for (int ni = 0; ni < NT; ni++) {
                float v = acc[mi][ni][r] + bias_c[ni];
                if (EPI == 2) v = fmaxf(v, 0.f);
                if (EPI == 0) outf[rb + ni * 16 + l15] = v;
                else          outb[rb + ni * 16 + l15] = __float2bfloat16(v);
            }
        }
}

// ---------------------------------------------------------------------------
// Weight transpose + f32->bf16: out[n][k] = in[k][n]. One 32x32 tile/block.
// ---------------------------------------------------------------------------
__global__ __launch_bounds__(256)
void transpose_cvt(const float* w0, const float* w1, const float* w2,
                   const float* w3, const float* w4, const float* w5,
                   __hip_bfloat16* o0, __hip_bfloat16* o1, __hip_bfloat16* o2,
                   __hip_bfloat16* o3, __hip_bfloat16* o4, __hip_bfloat16* o5)
{
    int t = blockIdx.x;
    const float* src; __hip_bfloat16* dst; int Kd, Nd, tl;
    if      (t < 64)  { src = w0; dst = o0; Kd = 256;  Nd = 256;  tl = t; }
    else if (t < 128) { src = w1; dst = o1; Kd = 256;  Nd = 256;  tl = t - 64; }
    else if (t < 160) { src = w2; dst = o2; Kd = 256;  Nd = 128;  tl = t - 128; }
    else if (t < 224) { src = w3; dst = o3; Kd = 256;  Nd = 256;  tl = t - 160; }
    else if (t < 480) { src = w4; dst = o4; Kd = 256;  Nd = 1024; tl = t - 224; }
    else              { src = w5; dst = o5; Kd = 1024; Nd = 256;  tl = t - 480; }
    int ntn = Nd >> 5;
    int kt = tl / ntn, nt = tl - kt * ntn;
    __shared__ float T[32][33];
    int tx = threadIdx.x & 31, ty = threadIdx.x >> 5;
#pragma unroll
    for (int i = 0; i < 4; i++) {
        int k = kt * 32 + ty + i * 8;
        T[tx][ty + i * 8] = src[(size_t)k * Nd + nt * 32 + tx];   // T[n_l][k_l]
    }
    __syncthreads();
#pragma unroll
    for (int i = 0; i < 4; i++) {
        int n = nt * 32 + ty + i * 8;
        dst[(size_t)n * Kd + kt * 32 + tx] = __float2bfloat16(T[ty + i * 8][tx]);
    }
}

// elementwise f32 -> bf16 (4/thread)
struct alignas(8) bh4 { __hip_bfloat16 a, b, c, d; };
__global__ __launch_bounds__(256)
void cvt4(const float* __restrict__ in, __hip_bfloat16* __restrict__ o, int n4)
{
    int i = blockIdx.x * 256 + threadIdx.x;
    if (i >= n4) return;
    float4 v = ((const float4*)in)[i];
    ((bh4*)o)[i] = { __float2bfloat16(v.x), __float2bfloat16(v.y),
                     __float2bfloat16(v.z), __float2bfloat16(v.w) };
}

// q = tgt + query_pos -> bf16 (4/thread)
__global__ __launch_bounds__(256)
void addcvt4(const float* __restrict__ a, const float* __restrict__ b,
             __hip_bfloat16* __restrict__ o, int n4)
{
    int i = blockIdx.x * 256 + threadIdx.x;
    if (i >= n4) return;
    float4 x = ((const float4*)a)[i];
    float4 y = ((const float4*)b)[i];
    ((bh4*)o)[i] = { __float2bfloat16(x.x + y.x), __float2bfloat16(x.y + y.y),
                     __float2bfloat16(x.z + y.z), __float2bfloat16(x.w + y.w) };
}

// ---------------------------------------------------------------------------
// Deformable bilinear sampling v2, two-phase.
// Block = 4 queries. Phase 1: 512 work items (q_l,h,l,p) -> 4 corner
// {pixel_row, weight} pairs in LDS. Phase 2: thread=(q_l,h,d8) gathers
// 4 channels per 8B load; {idx,w} broadcast from LDS across the 8-lane group.
// ---------------------------------------------------------------------------
#define QB 4
__global__ __launch_bounds__(256)
void sample_kernel(const float* __restrict__ refp, const float* __restrict__ offb,
                   const float* __restrict__ attn,
                   const __hip_bfloat16* __restrict__ value,
                   __hip_bfloat16* __restrict__ tgt2)
{
    __shared__ int2 spk[QB * 8 * 16 * 4];   // {pixel_row, weight-as-int}

    const int q0  = blockIdx.x * QB;
    const int tid = threadIdx.x;

    // ---- phase 1: coords/weights, one item per thread x2 ----
#pragma unroll
    for (int it = tid; it < QB * 8 * 16; it += 256) {
        const int ql = it >> 7, h = (it >> 4) & 7, lp = it & 15;
        const int l = lp >> 2, p = lp & 3;
        const int q = q0 + ql, b = q >> 13;
        const int Wl = 128 >> l;             // 128,64,32,16
        const int Hl = Wl;
        const int LSTART = (l == 0) ? 0 : (l == 1) ? 16384 : (l == 2) ? 20480 : 21504;

        const float rx = refp[((size_t)q * N_LEVELS + l) * 2 + 0];
        const float ry = refp[((size_t)q * N_LEVELS + l) * 2 + 1];
        const float ox = offb[(size_t)q * 256 + h * 32 + l * 8 + p * 2 + 0];
        const float oy = offb[(size_t)q * 256 + h * 32 + l * 8 + p * 2 + 1];
        const float a  = attn[(size_t)q * 128 + h * 16 + lp];

        const float x = rx * Wl - 0.5f + ox;
        const float y = ry * Hl - 0.5f + oy;
        const float x0f = floorf(x), y0f = floorf(y);
        const float wx = x - x0f, wy = y - y0f;
        const int ix = (int)x0f, iy = (int)y0f;
        const int base = b * S_TOTAL + LSTART;
        const float cw[4] = {(1.f - wx) * (1.f - wy) * a, wx * (1.f - wy) * a,
                             (1.f - wx) * wy * a,         wx * wy * a};
#pragma unroll
        for (int c = 0; c < 4; c++) {
            const int xi = ix + (c & 1), yi = iy + (c >> 1);
            const bool valid = ((unsigned)xi < (unsigned)Wl) && ((unsigned)yi < (unsigned)Hl);
            const float wv = valid ? cw[c] : 0.f;
            const int pix  = valid ? base + yi * Wl + xi : base;
            spk[it * 4 + c] = make_int2(pix, __float_as_int(wv));
        }
    }
    __syncthreads();

    // ---- phase 2: gather. thread = (ql, h, d8); 4 channels each ----
    const int ql = tid >> 6, h = (tid >> 3) & 7, d8 = tid & 7;
    const int q = q0 + ql;
    const int c0 = h * 32 + d8 * 4;
    const char* vb = (const char*)value + (size_t)c0 * 2;

    float a0 = 0.f, a1 = 0.f, a2 = 0.f, a3 = 0.f;
    const int sb = ((ql * 8 + h) * 16) * 4;
#pragma unroll
    for (int lp = 0; lp < 16; lp++)
#pragma unroll
        for (int c = 0; c < 4; c++) {
            int2 pk = spk[sb + lp * 4 + c];
            float wv = __int_as_float(pk.y);
            uint2 rv = *(const uint2*)(vb + ((size_t)(unsigned)pk.x << 9));
            a0 += wv * __uint_as_float(rv.x << 16);
            a1 += wv * __uint_as_float(rv.x & 0xffff0000u);
            a2 += wv * __uint_as_float(rv.y << 16);
            a3 += wv * __uint_as_float(rv.y & 0xffff0000u);
        }

    ((bh4*)(tgt2 + (size_t)q * 256 + c0))[0] =
        { __float2bfloat16(a0), __float2bfloat16(a1),
          __float2bfloat16(a2), __float2bfloat16(a3) };
}

// ---------------------------------------------------------------------------
extern "C" void kernel_launch(void* const* d_in, const int* in_sizes, int n_in,
                              void* d_out, int out_size, void* d_ws, size_t ws_size,
                              hipStream_t stream) {
    const float* tgt     = (const float*)d_in[0];
    const float* qpos    = (const float*)d_in[1];
    const float* refp    = (const float*)d_in[2];
    const float* src     = (const float*)d_in[3];
    const float* W_value = (const float*)d_in[6];
    const float* b_value = (const float*)d_in[7];
    const float* W_off   = (const float*)d_in[8];
    const float* b_off   = (const float*)d_in[9];
    const float* W_attn  = (const float*)d_in[10];
    const float* b_attn  = (const float*)d_in[11];
    const float* W_out   = (const float*)d_in[12];
    const float* b_out   = (const float*)d_in[13];
    const float* ln1_g   = (const float*)d_in[14];
    const float* ln1_b   = (const float*)d_in[15];
    const float* W1      = (const float*)d_in[16];
    const float* b1      = (const float*)d_in[17];
    const float* W2      = (const float*)d_in[18];
    const float* b2      = (const float*)d_in[19];
    const float* ln3_g   = (const float*)d_in[20];
    const float* ln3_b   = (const float*)d_in[21];
    float* out = (float*)d_out;

    // workspace layout
    char* p = (char*)d_ws;
    auto nxt = [&](size_t b) { char* r = p; p += (b + 255) & ~(size_t)255; return r; };
    __hip_bfloat16* Wvt    = (__hip_bfloat16*)nxt((size_t)256 * 256 * 2);
    __hip_bfloat16* Woat   = (__hip_bfloat16*)nxt((size_t)384 * 256 * 2);  // W_off^T ++ W_attn^T
    __hip_bfloat16* Woutt  = (__hip_bfloat16*)nxt((size_t)256 * 256 * 2);
    __hip_bfloat16* W1t    = (__hip_bfloat16*)nxt((size_t)1024 * 256 * 2);
    __hip_bfloat16* W2t    = (__hip_bfloat16*)nxt((size_t)256 * 1024 * 2);
    __hip_bfloat16* srcb   = (__hip_bfloat16*)nxt((size_t)M_V * 256 * 2);
    __hip_bfloat16* qb     = (__hip_bfloat16*)nxt((size_t)M_Q * 256 * 2);
    __hip_bfloat16* valueb = (__hip_bfloat16*)nxt((size_t)M_V * 256 * 2);
    float*          offb   = (float*)nxt((size_t)M_Q * 256 * 4);
    float*          attnb  = (float*)nxt((size_t)M_Q * 128 * 4);
    __hip_bfloat16* tgt2b  = (__hip_bfloat16*)nxt((size_t)M_Q * 256 * 2);
    float*          x      = (float*)nxt((size_t)M_Q * 256 * 4);
    __hip_bfloat16* xb     = (__hip_bfloat16*)nxt((size_t)M_Q * 256 * 2);
    __hip_bfloat16* hb     = (__hip_bfloat16*)nxt((size_t)M_Q * 1024 * 2);

    dim3 blk(256);

    // 0) weight transpose+cvt, activation converts
    transpose_cvt<<<dim3(736), blk, 0, stream>>>(W_value, W_off, W_attn, W_out, W1, W2,
                                                 Wvt, Woat, Woat + 256 * 256, Woutt, W1t, W2t);
    cvt4<<<dim3((M_V * 256 / 4 + 255) / 256), blk, 0, stream>>>(src, srcb, M_V * 256 / 4);
    addcvt4<<<dim3((M_Q * 256 / 4 + 255) / 256), blk, 0, stream>>>(tgt, qpos, qb, M_Q * 256 / 4);

    // 1) value = src @ W_value + b_value  -> bf16   (680 blocks)
    mfma_gemm<128, 128, 1><<<dim3(M_V / 128, 2), blk, 0, stream>>>(
        srcb, Wvt, b_value, nullptr, nullptr, nullptr, nullptr,
        nullptr, valueb, nullptr, 256, 256);

    // 2+3) off (f32) + attn (softmax16, f32) merged, N=384  (384 blocks)
    mfma_gemm<128, 128, 5><<<dim3(M_Q / 128, 3), blk, 0, stream>>>(
        qb, Woat, b_off, b_attn, nullptr, nullptr, nullptr,
        offb, nullptr, attnb, 256, 256);

    // 4) deformable sampling -> tgt2 (bf16)
    sample_kernel<<<dim3(M_Q / QB), blk, 0, stream>>>(refp, offb, attnb, valueb, tgt2b);

    // 5) x = LN1(tgt + tgt2 @ W_out + b_out) -> f32 + bf16  (256 blocks)
    mfma_gemm<64, 256, 4><<<dim3(M_Q / 64, 1), blk, 0, stream>>>(
        tgt2b, Woutt, b_out, nullptr, tgt, ln1_g, ln1_b, x, xb, nullptr, 256, 256);

    // 6) h = relu(x @ W1 + b1) -> bf16  (1024 blocks)
    mfma_gemm<128, 128, 2><<<dim3(M_Q / 128, 8), blk, 0, stream>>>(
        xb, W1t, b1, nullptr, nullptr, nullptr, nullptr,
        nullptr, hb, nullptr, 256, 1024);

    // 7) out = LN3(x + h @ W2 + b2) -> f32  (256 blocks)
    mfma_gemm<64, 256, 4><<<dim3(M_Q / 64, 1), blk, 0, stream>>>(
        hb, W2t, b2, nullptr, x, ln3_g, ln3_b, out, nullptr, nullptr, 1024, 256);
}

// Round 4
// 306.759 us; speedup vs baseline: 3.3052x; 1.0249x over previous
//
#include <hip/hip_runtime.h>
#include <hip/hip_bf16.h>
#include <math.h>

// Problem constants (fixed by setup_inputs)
#define D_MODEL   256
#define D_FFN     1024
#define N_LEVELS  4
#define N_HEADS   8
#define N_POINTS  4
#define BATCH     2
#define LQ        8192
#define S_TOTAL   21760            // 128*128 + 64*64 + 32*32 + 16*16
#define M_Q       (BATCH*LQ)       // 16384
#define M_V       (BATCH*S_TOTAL)  // 43520
#define VTILES    (M_V/128)        // 340

typedef __attribute__((ext_vector_type(8))) short bf16x8;   // 8 bf16 = 4 VGPRs
typedef __attribute__((ext_vector_type(4))) float floatx4;  // mfma C/D

struct alignas(8)  bh4 { __hip_bfloat16 a, b, c, d; };
struct alignas(16) bh8 { __hip_bfloat16 v[8]; };

__device__ __forceinline__ void gld_lds16(const void* g, void* l) {
    __builtin_amdgcn_global_load_lds(
        (const __attribute__((address_space(1))) void*)g,
        (__attribute__((address_space(3))) void*)l, 16, 0, 0);
}

// ---------------------------------------------------------------------------
// Core bf16 MFMA K-loop, double-buffered LDS, ONE barrier per K-iteration.
// Block tile BM x BN, 4 waves on M. v_mfma_f32_16x16x32_bf16, BK=32,
// global_load_lds(16B) staging. Bt is [N][K].
//  A frag: lane holds A[m=lane&15][k=quad*8+j]  (16B contiguous LDS row)
//  B frag: lane holds B[k=quad*8+j][n=lane&15]  (Bt LDS row [n][k])
//  C/D:    col=lane&15, row=quad*4+reg
// ---------------------------------------------------------------------------
template<int BM, int BN, int K>
__device__ __forceinline__ void gemm_core(const __hip_bfloat16* __restrict__ A,
                                          const __hip_bfloat16* __restrict__ Bt,
                                          int row0, int nb0,
                                          short* As, short* Bs,          // [2][BM*32], [2][BN*32]
                                          floatx4 (&acc)[BM/64][BN/16])
{
    constexpr int NT  = BN / 16;
    constexpr int AF  = BM / 64;
    constexpr int BCH = BN / 64;
    constexpr int NIT = K / 32;

    const int tid  = threadIdx.x;
    const int w    = tid >> 6;
    const int lane = tid & 63;
    const int quad = lane >> 4;
    const int l15  = lane & 15;
    const size_t K2 = (size_t)K * 2;

    const char* gA[AF]; int lA[AF];
#pragma unroll
    for (int i = 0; i < AF; i++) {
        int o = (w * AF + i) * 1024 + lane * 16;
        gA[i] = (const char*)A + (size_t)(row0 + (o >> 6)) * K2 + (o & 63);
        lA[i] = (w * AF + i) * 512;
    }
    const char* gB[BCH]; int lB[BCH];
#pragma unroll
    for (int j = 0; j < BCH; j++) {
        int o = (w * BCH + j) * 1024 + lane * 16;
        gB[j] = (const char*)Bt + (size_t)(nb0 + (o >> 6)) * K2 + (o & 63);
        lB[j] = (w * BCH + j) * 512;
    }

    // prologue: stage K-tile 0 into buffer 0
#pragma unroll
    for (int i = 0; i < AF; i++)  gld_lds16(gA[i], &As[lA[i]]);
#pragma unroll
    for (int j = 0; j < BCH; j++) gld_lds16(gB[j], &Bs[lB[j]]);

#pragma unroll 8
    for (int it = 0; it < NIT; ++it) {
        __syncthreads();                     // buf[it&1] staged; buf[it&1^1] free
        const int cb = it & 1;
        if (it + 1 < NIT) {                  // prefetch next tile into other buf
            const size_t kb = (size_t)(it + 1) * 64;   // 32 k * 2 B
            const int nb = cb ^ 1;
#pragma unroll
            for (int i = 0; i < AF; i++)  gld_lds16(gA[i] + kb, &As[nb * BM * 32 + lA[i]]);
#pragma unroll
            for (int j = 0; j < BCH; j++) gld_lds16(gB[j] + kb, &Bs[nb * BN * 32 + lB[j]]);
        }
        const short* Ab = &As[cb * BM * 32];
        const short* Bb = &Bs[cb * BN * 32];
        bf16x8 af[AF];
#pragma unroll
        for (int mi = 0; mi < AF; mi++)
            af[mi] = *(const bf16x8*)&Ab[(w * (AF * 16) + mi * 16 + l15) * 32 + quad * 8];
#pragma unroll
        for (int ni = 0; ni < NT; ni++) {
            bf16x8 bfr = *(const bf16x8*)&Bb[(ni * 16 + l15) * 32 + quad * 8];
#pragma unroll
            for (int mi = 0; mi < AF; mi++)
                acc[mi][ni] = __builtin_amdgcn_mfma_f32_16x16x32_bf16(af[mi], bfr, acc[mi][ni], 0, 0, 0);
        }
    }
}

// ---------------------------------------------------------------------------
// Generic GEMM kernel. EPI: 2 = relu->bf16 ; 4 = residual+LayerNorm(256)->f32
// (+optional bf16 copy, BN==256, nb0==0)
// ---------------------------------------------------------------------------
template<int BM, int BN, int K, int EPI>
__global__ __launch_bounds__(256)
void mfma_gemm(const __hip_bfloat16* __restrict__ A,
               const __hip_bfloat16* __restrict__ Bt,
               const float* __restrict__ bias,
               const float* __restrict__ resid,
               const float* __restrict__ lng, const float* __restrict__ lnb,
               float* __restrict__ outf, __hip_bfloat16* __restrict__ outb,
               int ldOut)
{
    constexpr int NT = BN / 16, AF = BM / 64;
    __shared__ alignas(16) short As[2 * BM * 32];
    __shared__ alignas(16) short Bs[2 * BN * 32];

    const int tid = threadIdx.x, w = tid >> 6, lane = tid & 63;
    const int quad = lane >> 4, l15 = lane & 15;
    const int row0 = blockIdx.x * BM, nb0 = blockIdx.y * BN;

    floatx4 acc[AF][NT];
#pragma unroll
    for (int mi = 0; mi < AF; mi++)
#pragma unroll
        for (int ni = 0; ni < NT; ni++) acc[mi][ni] = (floatx4){0.f, 0.f, 0.f, 0.f};

    gemm_core<BM, BN, K>(A, Bt, row0, nb0, As, Bs, acc);

    float bias_c[NT];
#pragma unroll
    for (int ni = 0; ni < NT; ni++) bias_c[ni] = bias[nb0 + ni * 16 + l15];

    if (EPI == 4) {
        float gv[NT], bv[NT];
#pragma unroll
        for (int ni = 0; ni < NT; ni++) { gv[ni] = lng[ni * 16 + l15]; bv[ni] = lnb[ni * 16 + l15]; }
#pragma unroll
        for (int mi = 0; mi < AF; mi++)
#pragma unroll
            for (int r = 0; r < 4; r++) {
                int row = row0 + w * (AF * 16) + mi * 16 + quad * 4 + r;
                size_t rb = (size_t)row * 256;
                float s = 0.f, sq = 0.f, vv[NT];
#pragma unroll
                for (int ni = 0; ni < NT; ni++) {
                    float v = acc[mi][ni][r] + bias_c[ni] + resid[rb + ni * 16 + l15];
                    vv[ni] = v; s += v; sq += v * v;
                }
#pragma unroll
                for (int msk = 1; msk <= 8; msk <<= 1) {
                    s += __shfl_xor(s, msk); sq += __shfl_xor(sq, msk);
                }
                float mean = s * (1.f / 256.f);
                float var  = sq * (1.f / 256.f) - mean * mean;
                float rstd = rsqrtf(var + 1e-5f);
#pragma unroll
                for (int ni = 0; ni < NT; ni++) {
                    float o = (vv[ni] - mean) * rstd * gv[ni] + bv[ni];
                    outf[rb + ni * 16 + l15] = o;
                    if (outb) outb[rb + ni * 16 + l15] = __float2bfloat16(o);
                }
            }
        return;
    }

    // EPI == 2: relu -> bf16
#pragma unroll
    for (int mi = 0; mi < AF; mi++)
#pragma unroll
        for (int r = 0; r < 4; r++) {
            int row = row0 + w * (AF * 16) + mi * 16 + quad * 4 + r;
            size_t rb = (size_t)row * ldOut + nb0;
#pragma unroll
            for (int ni = 0; ni < NT; ni++) {
                float v = fmaxf(acc[mi][ni][r] + bias_c[ni], 0.f);
                outb[rb + ni * 16 + l15] = __float2bfloat16(v);
            }
        }
}

// ---------------------------------------------------------------------------
// Merged value-projection + off/attn GEMM (independent ops, one dispatch).
// grid = (VTILES + 128, 3). x < VTILES: value (y<2, N=256, bf16 out).
// x >= VTILES: q @ [W_off^T ++ W_attn^T] (y<2 -> off f32; y==2 -> softmax16).
// ---------------------------------------------------------------------------
__global__ __launch_bounds__(256)
void mfma_gemm_vq(const __hip_bfloat16* __restrict__ srcb,
                  const __hip_bfloat16* __restrict__ Wvt,
                  const float* __restrict__ b_value,
                  __hip_bfloat16* __restrict__ valueb,
                  const __hip_bfloat16* __restrict__ qb,
                  const __hip_bfloat16* __restrict__ Woat,
                  const float* __restrict__ b_off, const float* __restrict__ b_attn,
                  float* __restrict__ offb, float* __restrict__ attnb)
{
    __shared__ alignas(16) short As[2 * 128 * 32];
    __shared__ alignas(16) short Bs[2 * 128 * 32];

    const bool isV = blockIdx.x < VTILES;
    if (isV && blockIdx.y == 2) return;

    const int tid = threadIdx.x, w = tid >> 6, lane = tid & 63;
    const int quad = lane >> 4, l15 = lane & 15;
    const int nb0 = blockIdx.y * 128;

    floatx4 acc[2][8];
#pragma unroll
    for (int mi = 0; mi < 2; mi++)
#pragma unroll
        for (int ni = 0; ni < 8; ni++) acc[mi][ni] = (floatx4){0.f, 0.f, 0.f, 0.f};

    if (isV) {
        const int row0 = blockIdx.x * 128;
        gemm_core<128, 128, 256>(srcb, Wvt, row0, nb0, As, Bs, acc);
        float bias_c[8];
#pragma unroll
        for (int ni = 0; ni < 8; ni++) bias_c[ni] = b_value[nb0 + ni * 16 + l15];
#pragma unroll
        for (int mi = 0; mi < 2; mi++)
#pragma unroll
            for (int r = 0; r < 4; r++) {
                int row = row0 + w * 32 + mi * 16 + quad * 4 + r;
                size_t rb = (size_t)row * 256 + nb0;
#pragma unroll
                for (int ni = 0; ni < 8; ni++)
                    valueb[rb + ni * 16 + l15] = __float2bfloat16(acc[mi][ni][r] + bias_c[ni]);
            }
        return;
    }

    const int row0 = (blockIdx.x - VTILES) * 128;
    gemm_core<128, 128, 256>(qb, Woat, row0, nb0, As, Bs, acc);

    if (blockIdx.y < 2) {    // offsets, f32, ld 256
        float bias_c[8];
#pragma unroll
        for (int ni = 0; ni < 8; ni++) bias_c[ni] = b_off[nb0 + ni * 16 + l15];
#pragma unroll
        for (int mi = 0; mi < 2; mi++)
#pragma unroll
            for (int r = 0; r < 4; r++) {
                int row = row0 + w * 32 + mi * 16 + quad * 4 + r;
                size_t rb = (size_t)row * 256 + nb0;
#pragma unroll
                for (int ni = 0; ni < 8; ni++)
                    offb[rb + ni * 16 + l15] = acc[mi][ni][r] + bias_c[ni];
            }
    } else {                 // attn: group-softmax(16) -> ld 128
        float bias_c[8];
#pragma unroll
        for (int ni = 0; ni < 8; ni++) bias_c[ni] = b_attn[ni * 16 + l15];
#pragma unroll
        for (int mi = 0; mi < 2; mi++)
#pragma unroll
            for (int r = 0; r < 4; r++) {
                int row = row0 + w * 32 + mi * 16 + quad * 4 + r;
                size_t rb = (size_t)row * 128;
#pragma unroll
                for (int ni = 0; ni < 8; ni++) {
                    float v = acc[mi][ni][r] + bias_c[ni];
                    float m = v;
#pragma unroll
                    for (int msk = 1; msk <= 8; msk <<= 1) m = fmaxf(m, __shfl_xor(m, msk));
                    float e = __expf(v - m);
                    float ssum = e;
#pragma unroll
                    for (int msk = 1; msk <= 8; msk <<= 1) ssum += __shfl_xor(ssum, msk);
                    attnb[rb + ni * 16 + l15] = e / ssum;
                }
            }
    }
}

// ---------------------------------------------------------------------------
// Prep: weight transpose+cvt (736 tiles) ++ src cvt (10880) ++ q add-cvt (4096)
// ---------------------------------------------------------------------------
__global__ __launch_bounds__(256)
void prep_kernel(const float* w0, const float* w1, const float* w2,
                 const float* w3, const float* w4, const float* w5,
                 __hip_bfloat16* o0, __hip_bfloat16* o1, __hip_bfloat16* o2,
                 __hip_bfloat16* o3, __hip_bfloat16* o4, __hip_bfloat16* o5,
                 const float* src, __hip_bfloat16* srcb,
                 const float* tgt, const float* qpos, __hip_bfloat16* qb)
{
    const int bx = blockIdx.x;
    if (bx < 736) {
        int t = bx;
        const float* s; __hip_bfloat16* dst; int Kd, Nd, tl;
        if      (t < 64)  { s = w0; dst = o0; Kd = 256;  Nd = 256;  tl = t; }
        else if (t < 128) { s = w1; dst = o1; Kd = 256;  Nd = 256;  tl = t - 64; }
        else if (t < 160) { s = w2; dst = o2; Kd = 256;  Nd = 128;  tl = t - 128; }
        else if (t < 224) { s = w3; dst = o3; Kd = 256;  Nd = 256;  tl = t - 160; }
        else if (t < 480) { s = w4; dst = o4; Kd = 256;  Nd = 1024; tl = t - 224; }
        else              { s = w5; dst = o5; Kd = 1024; Nd = 256;  tl = t - 480; }
        int ntn = Nd >> 5;
        int kt = tl / ntn, nt = tl - kt * ntn;
        __shared__ float T[32][33];
        int tx = threadIdx.x & 31, ty = threadIdx.x >> 5;
#pragma unroll
        for (int i = 0; i < 4; i++) {
            int k = kt * 32 + ty + i * 8;
            T[tx][ty + i * 8] = s[(size_t)k * Nd + nt * 32 + tx];
        }
        __syncthreads();
#pragma unroll
        for (int i = 0; i < 4; i++) {
            int n = nt * 32 + ty + i * 8;
            dst[(size_t)n * Kd + kt * 32 + tx] = __float2bfloat16(T[ty + i * 8][tx]);
        }
    } else if (bx < 736 + 10880) {
        int i = (bx - 736) * 256 + threadIdx.x;          // < M_V*256/4
        float4 v = ((const float4*)src)[i];
        ((bh4*)srcb)[i] = { __float2bfloat16(v.x), __float2bfloat16(v.y),
                            __float2bfloat16(v.z), __float2bfloat16(v.w) };
    } else {
        int i = (bx - 736 - 10880) * 256 + threadIdx.x;  // < M_Q*256/4
        float4 x = ((const float4*)tgt)[i];
        float4 y = ((const float4*)qpos)[i];
        ((bh4*)qb)[i] = { __float2bfloat16(x.x + y.x), __float2bfloat16(x.y + y.y),
                          __float2bfloat16(x.z + y.z), __float2bfloat16(x.w + y.w) };
    }
}

// ---------------------------------------------------------------------------
// Deformable bilinear sampling v3. Block = 8 queries.
// Phase 1: items (ql,h,l,p) -> 4 corner {pixel_row, weight} in LDS laid out
// [corner-slot][group] (stride 65 kills the 512B-stride bank aliasing).
// Phase 2: thread=(ql,h,d4) gathers 8 channels per 16B load.
// ---------------------------------------------------------------------------
#define QB 8
__global__ __launch_bounds__(256)
void sample_kernel(const float* __restrict__ refp, const float* __restrict__ offb,
                   const float* __restrict__ attn,
                   const __hip_bfloat16* __restrict__ value,
                   __hip_bfloat16* __restrict__ tgt2)
{
    __shared__ int2 spk[64 * 65];           // [sc=lp*4+c][g=ql*8+h], stride 65

    const int q0  = blockIdx.x * QB;
    const int tid = threadIdx.x;

    // ---- phase 1 ----
#pragma unroll
    for (int k = 0; k < 4; k++) {
        const int it = tid + k * 256;        // (ql,h,lp)
        const int ql = it >> 7, h = (it >> 4) & 7, lp = it & 15;
        const int l = lp >> 2, p = lp & 3;
        const int q = q0 + ql, b = q >> 13;
        const int Wl = 128 >> l;
        const int LST = (l == 0) ? 0 : (l == 1) ? 16384 : (l == 2) ? 20480 : 21504;

        const float rx = refp[((size_t)q * N_LEVELS + l) * 2 + 0];
        const float ry = refp[((size_t)q * N_LEVELS + l) * 2 + 1];
        const float ox = offb[(size_t)q * 256 + h * 32 + l * 8 + p * 2 + 0];
        const float oy = offb[(size_t)q * 256 + h * 32 + l * 8 + p * 2 + 1];
        const float a  = attn[(size_t)q * 128 + h * 16 + lp];

        const float x = rx * Wl - 0.5f + ox;
        const float y = ry * Wl - 0.5f + oy;
        const float x0f = floorf(x), y0f = floorf(y);
        const float wx = x - x0f, wy = y - y0f;
        const int ix = (int)x0f, iy = (int)y0f;
        const int base = b * S_TOTAL + LST;
        const int g = ql * 8 + h;
        const float cw[4] = {(1.f - wx) * (1.f - wy) * a, wx * (1.f - wy) * a,
                             (1.f - wx) * wy * a,         wx * wy * a};
#pragma unroll
        for (int c = 0; c < 4; c++) {
            const int xi = ix + (c & 1), yi = iy + (c >> 1);
            const bool valid = ((unsigned)xi < (unsigned)Wl) && ((unsigned)yi < (unsigned)Wl);
            spk[(lp * 4 + c) * 65 + g] =
                make_int2(valid ? base + yi * Wl + xi : base,
                          __float_as_int(valid ? cw[c] : 0.f));
        }
    }
    __syncthreads();

    // ---- phase 2 ----
    const int ql = tid >> 5, h = (tid >> 2) & 7, d4 = tid & 3;
    const int q = q0 + ql, g = ql * 8 + h;
    const int c0 = h * 32 + d4 * 8;
    const char* vb = (const char*)value + (size_t)c0 * 2;

    float ac[8] = {0.f, 0.f, 0.f, 0.f, 0.f, 0.f, 0.f, 0.f};
#pragma unroll
    for (int sc = 0; sc < 64; sc++) {
        int2 pk = spk[sc * 65 + g];
        float wv = __int_as_float(pk.y);
        uint4 rv = *(const uint4*)(vb + ((size_t)(unsigned)pk.x << 9));
        ac[0] += wv * __uint_as_float(rv.x << 16);
        ac[1] += wv * __uint_as_float(rv.x & 0xffff0000u);
        ac[2] += wv * __uint_as_float(rv.y << 16);
        ac[3] += wv * __uint_as_float(rv.y & 0xffff0000u);
        ac[4] += wv * __uint_as_float(rv.z << 16);
        ac[5] += wv * __uint_as_float(rv.z & 0xffff0000u);
        ac[6] += wv * __uint_as_float(rv.w << 16);
        ac[7] += wv * __uint_as_float(rv.w & 0xffff0000u);
    }
    bh8 o;
#pragma unroll
    for (int i = 0; i < 8; i++) o.v[i] = __float2bfloat16(ac[i]);
    *(bh8*)(tgt2 + (size_t)q * 256 + c0) = o;
}

// ---------------------------------------------------------------------------
extern "C" void kernel_launch(void* const* d_in, const int* in_sizes, int n_in,
                              void* d_out, int out_size, void* d_ws, size_t ws_size,
                              hipStream_t stream) {
    const float* tgt     = (const float*)d_in[0];
    const float* qpos    = (const float*)d_in[1];
    const float* refp    = (const float*)d_in[2];
    const float* src     = (const float*)d_in[3];
    const float* W_value = (const float*)d_in[6];
    const float* b_value = (const float*)d_in[7];
    const float* W_off   = (const float*)d_in[8];
    const float* b_off   = (const float*)d_in[9];
    const float* W_attn  = (const float*)d_in[10];
    const float* b_attn  = (const float*)d_in[11];
    const float* W_out   = (const float*)d_in[12];
    const float* b_out   = (const float*)d_in[13];
    const float* ln1_g   = (const float*)d_in[14];
    const float* ln1_b   = (const float*)d_in[15];
    const float* W1      = (const float*)d_in[16];
    const float* b1      = (const float*)d_in[17];
    const float* W2      = (const float*)d_in[18];
    const float* b2      = (const float*)d_in[19];
    const float* ln3_g   = (const float*)d_in[20];
    const float* ln3_b   = (const float*)d_in[21];
    float* out = (float*)d_out;

    // workspace layout
    char* p = (char*)d_ws;
    auto nxt = [&](size_t b) { char* r = p; p += (b + 255) & ~(size_t)255; return r; };
    __hip_bfloat16* Wvt    = (__hip_bfloat16*)nxt((size_t)256 * 256 * 2);
    __hip_bfloat16* Woat   = (__hip_bfloat16*)nxt((size_t)384 * 256 * 2);  // W_off^T ++ W_attn^T
    __hip_bfloat16* Woutt  = (__hip_bfloat16*)nxt((size_t)256 * 256 * 2);
    __hip_bfloat16* W1t    = (__hip_bfloat16*)nxt((size_t)1024 * 256 * 2);
    __hip_bfloat16* W2t    = (__hip_bfloat16*)nxt((size_t)256 * 1024 * 2);
    __hip_bfloat16* srcb   = (__hip_bfloat16*)nxt((size_t)M_V * 256 * 2);
    __hip_bfloat16* qb     = (__hip_bfloat16*)nxt((size_t)M_Q * 256 * 2);
    __hip_bfloat16* valueb = (__hip_bfloat16*)nxt((size_t)M_V * 256 * 2);
    float*          offb   = (float*)nxt((size_t)M_Q * 256 * 4);
    float*          attnb  = (float*)nxt((size_t)M_Q * 128 * 4);
    __hip_bfloat16* tgt2b  = (__hip_bfloat16*)nxt((size_t)M_Q * 256 * 2);
    float*          x      = (float*)nxt((size_t)M_Q * 256 * 4);
    __hip_bfloat16* xb     = (__hip_bfloat16*)nxt((size_t)M_Q * 256 * 2);
    __hip_bfloat16* hb     = (__hip_bfloat16*)nxt((size_t)M_Q * 1024 * 2);

    dim3 blk(256);

    // 0) prep: weight transpose+cvt ++ src cvt ++ q add-cvt  (one dispatch)
    prep_kernel<<<dim3(736 + 10880 + 4096), blk, 0, stream>>>(
        W_value, W_off, W_attn, W_out, W1, W2,
        Wvt, Woat, Woat + 256 * 256, Woutt, W1t, W2t,
        src, srcb, tgt, qpos, qb);

    // 1) value GEMM ++ off/attn GEMM  (one dispatch)
    mfma_gemm_vq<<<dim3(VTILES + M_Q / 128, 3), blk, 0, stream>>>(
        srcb, Wvt, b_value, valueb, qb, Woat, b_off, b_attn, offb, attnb);

    // 2) deformable sampling -> tgt2 (bf16)
    sample_kernel<<<dim3(M_Q / QB), blk, 0, stream>>>(refp, offb, attnb, valueb, tgt2b);

    // 3) x = LN1(tgt + tgt2 @ W_out + b_out) -> f32 + bf16
    mfma_gemm<64, 256, 256, 4><<<dim3(M_Q / 64, 1), blk, 0, stream>>>(
        tgt2b, Woutt, b_out, tgt, ln1_g, ln1_b, x, xb, 256);

    // 4) h = relu(x @ W1 + b1) -> bf16
    mfma_gemm<128, 128, 256, 2><<<dim3(M_Q / 128, 8), blk, 0, stream>>>(
        xb, W1t, b1, nullptr, nullptr, nullptr, nullptr, hb, 1024);

    // 5) out = LN3(x + h @ W2 + b2) -> f32
    mfma_gemm<64, 256, 1024, 4><<<dim3(M_Q / 64, 1), blk, 0, stream>>>(
        hb, W2t, b2, x, ln3_g, ln3_b, out, nullptr, 256);
}

// Round 6
// 301.221 us; speedup vs baseline: 3.3660x; 1.0184x over previous
//
#include <hip/hip_runtime.h>
#include <hip/hip_bf16.h>
#include <hip/hip_fp16.h>
#include <math.h>

// Problem constants (fixed by setup_inputs)
#define D_MODEL   256
#define D_FFN     1024
#define N_LEVELS  4
#define N_HEADS   8
#define N_POINTS  4
#define BATCH     2
#define LQ        8192
#define S_TOTAL   21760            // 128*128 + 64*64 + 32*32 + 16*16
#define M_Q       (BATCH*LQ)       // 16384
#define M_V       (BATCH*S_TOTAL)  // 43520
#define VTILES    (M_V/128)        // 340

typedef __attribute__((ext_vector_type(8))) short bf16x8;   // 8 bf16 = 4 VGPRs
typedef __attribute__((ext_vector_type(4))) float floatx4;  // mfma C/D

struct alignas(8)  bh4 { __hip_bfloat16 a, b, c, d; };
struct alignas(16) bh8 { __hip_bfloat16 v[8]; };

__device__ __forceinline__ void gld_lds16(const void* g, void* l) {
    __builtin_amdgcn_global_load_lds(
        (const __attribute__((address_space(1))) void*)g,
        (__attribute__((address_space(3))) void*)l, 16, 0, 0);
}

// ---------------------------------------------------------------------------
// Core bf16 MFMA K-loop, double-buffered LDS, ONE barrier per K-iteration.
// Block tile BM x BN, 4 waves on M. v_mfma_f32_16x16x32_bf16, BK=32,
// global_load_lds(16B) staging. Bt is [N][ldb]. A is [M][lda].
// ---------------------------------------------------------------------------
template<int BM, int BN, int K>
__device__ __forceinline__ void gemm_core(const __hip_bfloat16* __restrict__ A,
                                          const __hip_bfloat16* __restrict__ Bt,
                                          int row0, int nb0, int lda, int ldb,
                                          short* As, short* Bs,
                                          floatx4 (&acc)[BM/64][BN/16])
{
    constexpr int NT  = BN / 16;
    constexpr int AF  = BM / 64;
    constexpr int BCH = BN / 64;
    constexpr int NIT = K / 32;

    const int tid  = threadIdx.x;
    const int w    = tid >> 6;
    const int lane = tid & 63;
    const int quad = lane >> 4;
    const int l15  = lane & 15;
    const size_t ldaB = (size_t)lda * 2, ldbB = (size_t)ldb * 2;

    const char* gA[AF]; int lA[AF];
#pragma unroll
    for (int i = 0; i < AF; i++) {
        int o = (w * AF + i) * 1024 + lane * 16;
        gA[i] = (const char*)A + (size_t)(row0 + (o >> 6)) * ldaB + (o & 63);
        lA[i] = (w * AF + i) * 512;
    }
    const char* gB[BCH]; int lB[BCH];
#pragma unroll
    for (int j = 0; j < BCH; j++) {
        int o = (w * BCH + j) * 1024 + lane * 16;
        gB[j] = (const char*)Bt + (size_t)(nb0 + (o >> 6)) * ldbB + (o & 63);
        lB[j] = (w * BCH + j) * 512;
    }

    // prologue: stage K-tile 0 into buffer 0
#pragma unroll
    for (int i = 0; i < AF; i++)  gld_lds16(gA[i], &As[lA[i]]);
#pragma unroll
    for (int j = 0; j < BCH; j++) gld_lds16(gB[j], &Bs[lB[j]]);

#pragma unroll 8
    for (int it = 0; it < NIT; ++it) {
        __syncthreads();
        const int cb = it & 1;
        if (it + 1 < NIT) {
            const size_t kb = (size_t)(it + 1) * 64;   // 32 k * 2 B
            const int nb = cb ^ 1;
#pragma unroll
            for (int i = 0; i < AF; i++)  gld_lds16(gA[i] + kb, &As[nb * BM * 32 + lA[i]]);
#pragma unroll
            for (int j = 0; j < BCH; j++) gld_lds16(gB[j] + kb, &Bs[nb * BN * 32 + lB[j]]);
        }
        const short* Ab = &As[cb * BM * 32];
        const short* Bb = &Bs[cb * BN * 32];
        bf16x8 af[AF];
#pragma unroll
        for (int mi = 0; mi < AF; mi++)
            af[mi] = *(const bf16x8*)&Ab[(w * (AF * 16) + mi * 16 + l15) * 32 + quad * 8];
#pragma unroll
        for (int ni = 0; ni < NT; ni++) {
            bf16x8 bfr = *(const bf16x8*)&Bb[(ni * 16 + l15) * 32 + quad * 8];
#pragma unroll
            for (int mi = 0; mi < AF; mi++)
                acc[mi][ni] = __builtin_amdgcn_mfma_f32_16x16x32_bf16(af[mi], bfr, acc[mi][ni], 0, 0, 0);
        }
    }
}

// ---------------------------------------------------------------------------
// Generic GEMM. EPI: 0 = f32 out (+bias if non-null); 2 = relu -> bf16.
// blockIdx.z: K-split chunk — A/Bt advance by z*K, outf by z*zStride.
// ---------------------------------------------------------------------------
template<int BM, int BN, int K, int EPI>
__global__ __launch_bounds__(256)
void mfma_gemm(const __hip_bfloat16* __restrict__ A,
               const __hip_bfloat16* __restrict__ Bt,
               const float* __restrict__ bias,
               float* __restrict__ outf, __hip_bfloat16* __restrict__ outb,
               int lda, int ldb, int ldOut, long zStride)
{
    constexpr int NT = BN / 16, AF = BM / 64;
    __shared__ alignas(16) short As[2 * BM * 32];
    __shared__ alignas(16) short Bs[2 * BN * 32];

    const int tid = threadIdx.x, w = tid >> 6, lane = tid & 63;
    const int quad = lane >> 4, l15 = lane & 15;
    const int row0 = blockIdx.x * BM, nb0 = blockIdx.y * BN;
    const int z = blockIdx.z;

    floatx4 acc[AF][NT];
#pragma unroll
    for (int mi = 0; mi < AF; mi++)
#pragma unroll
        for (int ni = 0; ni < NT; ni++) acc[mi][ni] = (floatx4){0.f, 0.f, 0.f, 0.f};

    gemm_core<BM, BN, K>(A + (size_t)z * K, Bt + (size_t)z * K,
                         row0, nb0, lda, ldb, As, Bs, acc);

    float bias_c[NT];
#pragma unroll
    for (int ni = 0; ni < NT; ni++) bias_c[ni] = bias ? bias[nb0 + ni * 16 + l15] : 0.f;

    float* of = outf + (size_t)z * zStride;
#pragma unroll
    for (int mi = 0; mi < AF; mi++)
#pragma unroll
        for (int r = 0; r < 4; r++) {
            int row = row0 + w * (AF * 16) + mi * 16 + quad * 4 + r;
            size_t rb = (size_t)row * ldOut + nb0;
#pragma unroll
            for (int ni = 0; ni < NT; ni++) {
                float v = acc[mi][ni][r] + bias_c[ni];
                if (EPI == 2) outb[rb + ni * 16 + l15] = __float2bfloat16(fmaxf(v, 0.f));
                else          of[rb + ni * 16 + l15] = v;
            }
        }
}

// ---------------------------------------------------------------------------
// Merged value-projection + off/attn GEMM (independent ops, one dispatch).
// ---------------------------------------------------------------------------
__global__ __launch_bounds__(256)
void mfma_gemm_vq(const __hip_bfloat16* __restrict__ srcb,
                  const __hip_bfloat16* __restrict__ Wvt,
                  const float* __restrict__ b_value,
                  __hip_bfloat16* __restrict__ valueb,
                  const __hip_bfloat16* __restrict__ qb,
                  const __hip_bfloat16* __restrict__ Woat,
                  const float* __restrict__ b_off, const float* __restrict__ b_attn,
                  float* __restrict__ offb, float* __restrict__ attnb)
{
    __shared__ alignas(16) short As[2 * 128 * 32];
    __shared__ alignas(16) short Bs[2 * 128 * 32];

    const bool isV = blockIdx.x < VTILES;
    if (isV && blockIdx.y == 2) return;

    const int tid = threadIdx.x, w = tid >> 6, lane = tid & 63;
    const int quad = lane >> 4, l15 = lane & 15;
    const int nb0 = blockIdx.y * 128;

    floatx4 acc[2][8];
#pragma unroll
    for (int mi = 0; mi < 2; mi++)
#pragma unroll
        for (int ni = 0; ni < 8; ni++) acc[mi][ni] = (floatx4){0.f, 0.f, 0.f, 0.f};

    if (isV) {
        const int row0 = blockIdx.x * 128;
        gemm_core<128, 128, 256>(srcb, Wvt, row0, nb0, 256, 256, As, Bs, acc);
        float bias_c[8];
#pragma unroll
        for (int ni = 0; ni < 8; ni++) bias_c[ni] = b_value[nb0 + ni * 16 + l15];
#pragma unroll
        for (int mi = 0; mi < 2; mi++)
#pragma unroll
            for (int r = 0; r < 4; r++) {
                int row = row0 + w * 32 + mi * 16 + quad * 4 + r;
                size_t rb = (size_t)row * 256 + nb0;
#pragma unroll
                for (int ni = 0; ni < 8; ni++)
                    valueb[rb + ni * 16 + l15] = __float2bfloat16(acc[mi][ni][r] + bias_c[ni]);
            }
        return;
    }

    const int row0 = (blockIdx.x - VTILES) * 128;
    gemm_core<128, 128, 256>(qb, Woat, row0, nb0, 256, 256, As, Bs, acc);

    if (blockIdx.y < 2) {    // offsets, f32, ld 256
        float bias_c[8];
#pragma unroll
        for (int ni = 0; ni < 8; ni++) bias_c[ni] = b_off[nb0 + ni * 16 + l15];
#pragma unroll
        for (int mi = 0; mi < 2; mi++)
#pragma unroll
            for (int r = 0; r < 4; r++) {
                int row = row0 + w * 32 + mi * 16 + quad * 4 + r;
                size_t rb = (size_t)row * 256 + nb0;
#pragma unroll
                for (int ni = 0; ni < 8; ni++)
                    offb[rb + ni * 16 + l15] = acc[mi][ni][r] + bias_c[ni];
            }
    } else {                 // attn: group-softmax(16) -> ld 128
        float bias_c[8];
#pragma unroll
        for (int ni = 0; ni < 8; ni++) bias_c[ni] = b_attn[ni * 16 + l15];
#pragma unroll
        for (int mi = 0; mi < 2; mi++)
#pragma unroll
            for (int r = 0; r < 4; r++) {
                int row = row0 + w * 32 + mi * 16 + quad * 4 + r;
                size_t rb = (size_t)row * 128;
#pragma unroll
                for (int ni = 0; ni < 8; ni++) {
                    float v = acc[mi][ni][r] + bias_c[ni];
                    float m = v;
#pragma unroll
                    for (int msk = 1; msk <= 8; msk <<= 1) m = fmaxf(m, __shfl_xor(m, msk));
                    float e = __expf(v - m);
                    float ssum = e;
#pragma unroll
                    for (int msk = 1; msk <= 8; msk <<= 1) ssum += __shfl_xor(ssum, msk);
                    attnb[rb + ni * 16 + l15] = e / ssum;
                }
            }
    }
}

// ---------------------------------------------------------------------------
// Residual + LayerNorm, one wave per 256-col row.
// v = resid + in1 (+ in2) (+ bias); out f32 (+ optional bf16 copy).
// ---------------------------------------------------------------------------
__global__ __launch_bounds__(256)
void ln_kernel(const float* __restrict__ in1, const float* __restrict__ in2,
               const float* __restrict__ resid, const float* __restrict__ bias,
               const float* __restrict__ g, const float* __restrict__ b,
               float* __restrict__ outf, __hip_bfloat16* __restrict__ outb)
{
    const int row  = blockIdx.x * 4 + (threadIdx.x >> 6);
    const int lane = threadIdx.x & 63;
    const size_t rb = (size_t)row * 256 + lane * 4;

    float4 v = *(const float4*)(resid + rb);
    float4 a = *(const float4*)(in1 + rb);
    v.x += a.x; v.y += a.y; v.z += a.z; v.w += a.w;
    if (in2) {
        float4 c = *(const float4*)(in2 + rb);
        v.x += c.x; v.y += c.y; v.z += c.z; v.w += c.w;
    }
    if (bias) {
        float4 c = *(const float4*)(bias + lane * 4);
        v.x += c.x; v.y += c.y; v.z += c.z; v.w += c.w;
    }
    float s  = v.x + v.y + v.z + v.w;
    float sq = v.x * v.x + v.y * v.y + v.z * v.z + v.w * v.w;
#pragma unroll
    for (int msk = 1; msk <= 32; msk <<= 1) {
        s += __shfl_xor(s, msk); sq += __shfl_xor(sq, msk);
    }
    float mean = s * (1.f / 256.f);
    float var  = sq * (1.f / 256.f) - mean * mean;
    float rstd = rsqrtf(var + 1e-5f);
    float4 gg = *(const float4*)(g + lane * 4);
    float4 bb = *(const float4*)(b + lane * 4);
    float4 o;
    o.x = (v.x - mean) * rstd * gg.x + bb.x;
    o.y = (v.y - mean) * rstd * gg.y + bb.y;
    o.z = (v.z - mean) * rstd * gg.z + bb.z;
    o.w = (v.w - mean) * rstd * gg.w + bb.w;
    *(float4*)(outf + rb) = o;
    if (outb)
        *(bh4*)(outb + rb) = { __float2bfloat16(o.x), __float2bfloat16(o.y),
                               __float2bfloat16(o.z), __float2bfloat16(o.w) };
}

// ---------------------------------------------------------------------------
// Prep: weight transpose+cvt (736 tiles) ++ src cvt (10880) ++ q add-cvt (4096)
// ---------------------------------------------------------------------------
__global__ __launch_bounds__(256)
void prep_kernel(const float* w0, const float* w1, const float* w2,
                 const float* w3, const float* w4, const float* w5,
                 __hip_bfloat16* o0, __hip_bfloat16* o1, __hip_bfloat16* o2,
                 __hip_bfloat16* o3, __hip_bfloat16* o4, __hip_bfloat16* o5,
                 const float* src, __hip_bfloat16* srcb,
                 const float* tgt, const float* qpos, __hip_bfloat16* qb)
{
    const int bx = blockIdx.x;
    if (bx < 736) {
        int t = bx;
        const float* s; __hip_bfloat16* dst; int Kd, Nd, tl;
        if      (t < 64)  { s = w0; dst = o0; Kd = 256;  Nd = 256;  tl = t; }
        else if (t < 128) { s = w1; dst = o1; Kd = 256;  Nd = 256;  tl = t - 64; }
        else if (t < 160) { s = w2; dst = o2; Kd = 256;  Nd = 128;  tl = t - 128; }
        else if (t < 224) { s = w3; dst = o3; Kd = 256;  Nd = 256;  tl = t - 160; }
        else if (t < 480) { s = w4; dst = o4; Kd = 256;  Nd = 1024; tl = t - 224; }
        else              { s = w5; dst = o5; Kd = 1024; Nd = 256;  tl = t - 480; }
        int ntn = Nd >> 5;
        int kt = tl / ntn, nt = tl - kt * ntn;
        __shared__ float T[32][33];
        int tx = threadIdx.x & 31, ty = threadIdx.x >> 5;
#pragma unroll
        for (int i = 0; i < 4; i++) {
            int k = kt * 32 + ty + i * 8;
            T[tx][ty + i * 8] = s[(size_t)k * Nd + nt * 32 + tx];
        }
        __syncthreads();
#pragma unroll
        for (int i = 0; i < 4; i++) {
            int n = nt * 32 + ty + i * 8;
            dst[(size_t)n * Kd + kt * 32 + tx] = __float2bfloat16(T[ty + i * 8][tx]);
        }
    } else if (bx < 736 + 10880) {
        int i = (bx - 736) * 256 + threadIdx.x;
        float4 v = ((const float4*)src)[i];
        ((bh4*)srcb)[i] = { __float2bfloat16(v.x), __float2bfloat16(v.y),
                            __float2bfloat16(v.z), __float2bfloat16(v.w) };
    } else {
        int i = (bx - 736 - 10880) * 256 + threadIdx.x;
        float4 x = ((const float4*)tgt)[i];
        float4 y = ((const float4*)qpos)[i];
        ((bh4*)qb)[i] = { __float2bfloat16(x.x + y.x), __float2bfloat16(x.y + y.y),
                          __float2bfloat16(x.z + y.z), __float2bfloat16(x.w + y.w) };
    }
}

// ---------------------------------------------------------------------------
// Deformable bilinear sampling v4. Block = 8 queries, LDS packed to 4B/entry:
// [31:16] pixel row (< 43520 fits u16), [15:0] weight fp16.
// Phase 2: thread=(ql,h,d4) gathers 8 channels per 16B load.
// ---------------------------------------------------------------------------
#define QB 8
__global__ __launch_bounds__(256)
void sample_kernel(const float* __restrict__ refp, const float* __restrict__ offb,
                   const float* __restrict__ attn,
                   const __hip_bfloat16* __restrict__ value,
                   __hip_bfloat16* __restrict__ tgt2)
{
    __shared__ unsigned spk[64 * 65];       // [sc=lp*4+c][g=ql*8+h], stride 65

    const int q0  = blockIdx.x * QB;
    const int tid = threadIdx.x;

    // ---- phase 1 ----
#pragma unroll
    for (int k = 0; k < 4; k++) {
        const int it = tid + k * 256;        // (ql,h,lp)
        const int ql = it >> 7, h = (it >> 4) & 7, lp = it & 15;
        const int l = lp >> 2, p = lp & 3;
        const int q = q0 + ql, b = q >> 13;
        const int Wl = 128 >> l;
        const int LST = (l == 0) ? 0 : (l == 1) ? 16384 : (l == 2) ? 20480 : 21504;

        const float rx = refp[((size_t)q * N_LEVELS + l) * 2 + 0];
        const float ry = refp[((size_t)q * N_LEVELS + l) * 2 + 1];
        const float ox = offb[(size_t)q * 256 + h * 32 + l * 8 + p * 2 + 0];
        const float oy = offb[(size_t)q * 256 + h * 32 + l * 8 + p * 2 + 1];
        const float a  = attn[(size_t)q * 128 + h * 16 + lp];

        const float x = rx * Wl - 0.5f + ox;
        const float y = ry * Wl - 0.5f + oy;
        const float x0f = floorf(x), y0f = floorf(y);
        const float wx = x - x0f, wy = y - y0f;
        const int ix = (int)x0f, iy = (int)y0f;
        const int base = b * S_TOTAL + LST;
        const int g = ql * 8 + h;
        const float cw[4] = {(1.f - wx) * (1.f - wy) * a, wx * (1.f - wy) * a,
                             (1.f - wx) * wy * a,         wx * wy * a};
#pragma unroll
        for (int c = 0; c < 4; c++) {
            const int xi = ix + (c & 1), yi = iy + (c >> 1);
            const bool valid = ((unsigned)xi < (unsigned)Wl) && ((unsigned)yi < (unsigned)Wl);
            const unsigned pix = valid ? (unsigned)(base + yi * Wl + xi) : (unsigned)base;
            const __half hw = __float2half(valid ? cw[c] : 0.f);
            spk[(lp * 4 + c) * 65 + g] = (pix << 16) | (unsigned)__half_as_ushort(hw);
        }
    }
    __syncthreads();

    // ---- phase 2 ----
    const int ql = tid >> 5, h = (tid >> 2) & 7, d4 = tid & 3;
    const int q = q0 + ql, g = ql * 8 + h;
    const int c0 = h * 32 + d4 * 8;
    const char* vb = (const char*)value + (size_t)c0 * 2;

    float ac[8] = {0.f, 0.f, 0.f, 0.f, 0.f, 0.f, 0.f, 0.f};
#pragma unroll
    for (int sc = 0; sc < 64; sc++) {
        unsigned u = spk[sc * 65 + g];
        float wv = __half2float(__ushort_as_half((unsigned short)(u & 0xffffu)));
        uint4 rv = *(const uint4*)(vb + ((size_t)(u >> 16) << 9));
        ac[0] += wv * __uint_as_float(rv.x << 16);
        ac[1] += wv * __uint_as_float(rv.x & 0xffff0000u);
        ac[2] += wv * __uint_as_float(rv.y << 16);
        ac[3] += wv * __uint_as_float(rv.y & 0xffff0000u);
        ac[4] += wv * __uint_as_float(rv.z << 16);
        ac[5] += wv * __uint_as_float(rv.z & 0xffff0000u);
        ac[6] += wv * __uint_as_float(rv.w << 16);
        ac[7] += wv * __uint_as_float(rv.w & 0xffff0000u);
    }
    bh8 o;
#pragma unroll
    for (int i = 0; i < 8; i++) o.v[i] = __float2bfloat16(ac[i]);
    *(bh8*)(tgt2 + (size_t)q * 256 + c0) = o;
}

// ---------------------------------------------------------------------------
extern "C" void kernel_launch(void* const* d_in, const int* in_sizes, int n_in,
                              void* d_out, int out_size, void* d_ws, size_t ws_size,
                              hipStream_t stream) {
    const float* tgt     = (const float*)d_in[0];
    const float* qpos    = (const float*)d_in[1];
    const float* refp    = (const float*)d_in[2];
    const float* src     = (const float*)d_in[3];
    const float* W_value = (const float*)d_in[6];
    const float* b_value = (const float*)d_in[7];
    const float* W_off   = (const float*)d_in[8];
    const float* b_off   = (const float*)d_in[9];
    const float* W_attn  = (const float*)d_in[10];
    const float* b_attn  = (const float*)d_in[11];
    const float* W_out   = (const float*)d_in[12];
    const float* b_out   = (const float*)d_in[13];
    const float* ln1_g   = (const float*)d_in[14];
    const float* ln1_b   = (const float*)d_in[15];
    const float* W1      = (const float*)d_in[16];
    const float* b1      = (const float*)d_in[17];
    const float* W2      = (const float*)d_in[18];
    const float* b2      = (const float*)d_in[19];
    const float* ln3_g   = (const float*)d_in[20];
    const float* ln3_b   = (const float*)d_in[21];
    float* out = (float*)d_out;

    // workspace layout (with dead-buffer overlays)
    char* p = (char*)d_ws;
    auto nxt = [&](size_t b) { char* r = p; p += (b + 255) & ~(size_t)255; return r; };
    __hip_bfloat16* Wvt    = (__hip_bfloat16*)nxt((size_t)256 * 256 * 2);
    __hip_bfloat16* Woat   = (__hip_bfloat16*)nxt((size_t)384 * 256 * 2);
    __hip_bfloat16* Woutt  = (__hip_bfloat16*)nxt((size_t)256 * 256 * 2);
    __hip_bfloat16* W1t    = (__hip_bfloat16*)nxt((size_t)1024 * 256 * 2);
    __hip_bfloat16* W2t    = (__hip_bfloat16*)nxt((size_t)256 * 1024 * 2);
    __hip_bfloat16* srcb   = (__hip_bfloat16*)nxt((size_t)M_V * 256 * 2);  // dead after vq
    __hip_bfloat16* qb     = (__hip_bfloat16*)nxt((size_t)M_Q * 256 * 2);  // dead after vq
    __hip_bfloat16* valueb = (__hip_bfloat16*)nxt((size_t)M_V * 256 * 2);  // dead after sampler
    float*          offb   = (float*)nxt((size_t)M_Q * 256 * 4);           // dead after sampler
    float*          attnb  = (float*)nxt((size_t)M_Q * 128 * 4);
    __hip_bfloat16* tgt2b  = (__hip_bfloat16*)nxt((size_t)M_Q * 256 * 2);
    float*          x      = (float*)nxt((size_t)M_Q * 256 * 4);
    __hip_bfloat16* xb     = (__hip_bfloat16*)nxt((size_t)M_Q * 256 * 2);
    __hip_bfloat16* hb     = (__hip_bfloat16*)nxt((size_t)M_Q * 1024 * 2);
    // overlays (written only after their hosts are dead):
    float* t2o = offb;                          // out-proj result, over offb
    // FFN2 split-K partials: CONTIGUOUS region of 2 * M_Q*256 floats = 33.6 MB
    // starting at srcb; spans srcb (22.3 MB) + qb (8.4 MB) + head of valueb —
    // all dead by the FFN2 dispatch. zStride in the kernel = M_Q*256 floats,
    // so p1 MUST be exactly p0 + M_Q*256 (round-5 bug: p1 pointed elsewhere).
    float* p0  = (float*)srcb;
    float* p1  = p0 + (size_t)M_Q * 256;

    dim3 blk(256);

    // 0) prep
    prep_kernel<<<dim3(736 + 10880 + 4096), blk, 0, stream>>>(
        W_value, W_off, W_attn, W_out, W1, W2,
        Wvt, Woat, Woat + 256 * 256, Woutt, W1t, W2t,
        src, srcb, tgt, qpos, qb);

    // 1) value GEMM ++ off/attn GEMM
    mfma_gemm_vq<<<dim3(VTILES + M_Q / 128, 3), blk, 0, stream>>>(
        srcb, Wvt, b_value, valueb, qb, Woat, b_off, b_attn, offb, attnb);

    // 2) deformable sampling -> tgt2 (bf16)
    sample_kernel<<<dim3(M_Q / QB), blk, 0, stream>>>(refp, offb, attnb, valueb, tgt2b);

    // 3) t2o = tgt2 @ W_out + b_out   (512 blocks)
    mfma_gemm<64, 128, 256, 0><<<dim3(M_Q / 64, 2), blk, 0, stream>>>(
        tgt2b, Woutt, b_out, t2o, nullptr, 256, 256, 256, 0);

    // 4) x = LN1(tgt + t2o) -> f32 + bf16
    ln_kernel<<<dim3(M_Q / 4), blk, 0, stream>>>(
        t2o, nullptr, tgt, nullptr, ln1_g, ln1_b, x, xb);

    // 5) h = relu(x @ W1 + b1) -> bf16  (1024 blocks)
    mfma_gemm<128, 128, 256, 2><<<dim3(M_Q / 128, 8), blk, 0, stream>>>(
        xb, W1t, b1, nullptr, hb, 256, 256, 1024, 0);

    // 6) FFN2 split-K: p[z] = h[:, z*512:+512] @ W2t[:, z*512:+512]  (1024 blocks)
    mfma_gemm<64, 128, 512, 0><<<dim3(M_Q / 64, 2, 2), blk, 0, stream>>>(
        hb, W2t, nullptr, p0, nullptr, 1024, 1024, 256, (long)M_Q * 256);

    // 7) out = LN3(x + p0 + p1 + b2) -> f32
    ln_kernel<<<dim3(M_Q / 4), blk, 0, stream>>>(
        p0, p1, x, b2, ln3_g, ln3_b, out, nullptr);
}